// Round 3
// baseline (475.444 us; speedup 1.0000x reference)
//
#include <hip/hip_runtime.h>
#include <hip/hip_bf16.h>
#include <math.h>

// Problem constants
#define B_    8
#define T_    2048
#define NTOK  (B_ * T_)   // 16384 tokens
#define D_    512
#define E_    8
#define NPAIR 28          // unordered expert pairs (top-2 always distinct)
#define CAP   NTOK        // per-pair bucket capacity (worst case)

// worklist: wl[0] = total mtiles; wl[1+i] = (pair<<8)|mtile.
// Sum ceil(cnt_p/128) <= 128 + 27 = 155 -> pad to 160 (multiple of 8 for XCD map)
#define WL_MAX 160

// router: 1024 blocks x 256 thr; 16 tok/block, 4 tok/wave.
#define RV_TOK    16
#define RV_THR    256
#define XS_STRIDE 132
#define WS_FLOATS 2108

// fused prep kernel: router blocks + transpose blocks
#define PREP_ROUTER_BLOCKS (NTOK / RV_TOK)        // 1024
#define PREP_TRANS_BLOCKS  (16 * 16 * E_)          // 2048
#define PREP_BLOCKS (PREP_ROUTER_BLOCKS + PREP_TRANS_BLOCKS)  // 3072

typedef __attribute__((ext_vector_type(4))) float f32x4;
typedef __attribute__((ext_vector_type(8))) short short8;  // 8 bf16 (MFMA a/b frag)

__device__ __forceinline__ void async_load16(const void* g, void* l) {
    __builtin_amdgcn_global_load_lds(
        (const __attribute__((address_space(1))) unsigned int*)g,
        (__attribute__((address_space(3))) unsigned int*)l,
        16, 0, 0);
}

// ---------------------------------------------------------------------------
// Kernel 1 (fused prep): transpose_wk  U  router+bucket  U  build_wl.
//   R9: one launch replaces 4 (transpose, router, bucket, build_wl).
//   * blocks [0,1024): router v6 body; the 4 result-lanes/wave do the pair
//     atomic + entry write directly (top2 global buffer eliminated).
//   * blocks [1024,3072): Wk fp32 -> Wkt bf16 transpose (B^T layout).
//   * done-counter: last block to finish builds the worklist (wave 0).
// ---------------------------------------------------------------------------
__global__ __launch_bounds__(256) void prep_kernel(
    const float* __restrict__ x,     // [NTOK][D]
    const float* __restrict__ eps,   // [NTOK][E]
    const float* __restrict__ Wr,    // [D][E]
    const float* __restrict__ br,    // [E]
    const float* __restrict__ Wn,    // [D][E]
    const float* __restrict__ bn,    // [E]
    const float* __restrict__ Wk,    // [E][D][D]
    __hip_bfloat16* __restrict__ xb,   // out: [NTOK][D] bf16
    __hip_bfloat16* __restrict__ wkt,  // out: [E][D][D] bf16 (B^T)
    int* __restrict__ counts,          // [NPAIR] pre-zeroed
    uint4* __restrict__ entries,       // [NPAIR][CAP]
    int* __restrict__ done,            // pre-zeroed
    int* __restrict__ wl)              // [1+WL_MAX]
{
    __shared__ float smem[RV_TOK * XS_STRIDE + WS_FLOATS];  // 16.9 KB
    __shared__ int lastBlock;
    const int bid = blockIdx.x, tid = threadIdx.x;

    if (bid < PREP_ROUTER_BLOCKS) {
        // ------------------------- router body -------------------------
        float* xs  = smem;                         // [RV_TOK][XS_STRIDE]
        float* wsh = smem + RV_TOK * XS_STRIDE;    // skewed [128][16]

        const int tok0 = bid * RV_TOK;
        const int lane = tid & 63, wv = tid >> 6;
        const int kidx = lane >> 2, ts = lane & 3;
        const int tl = wv * 4 + ts;                // this lane's token
        const int wk = tid >> 1, wh = tid & 1;     // W stager: row, half

        float acc[16];  // [0..7]=x.Wr per expert, [8..15]=x.Wn
        #pragma unroll
        for (int c = 0; c < 16; ++c) acc[c] = 0.f;

        for (int kc = 0; kc < D_; kc += 128) {
            // stage x chunk [16 tok][128 k] + fused bf16 convert/store
            #pragma unroll
            for (int it = 0; it < 2; ++it) {
                const int f   = it * RV_THR + tid;      // f32x4 index in [0,512)
                const int row = f >> 5, col = (f & 31) * 4;
                const f32x4 v = *(const f32x4*)(x + (size_t)(tok0 + row) * D_ + kc + col);
                *(f32x4*)(xs + row * XS_STRIDE + col) = v;
                union { __hip_bfloat16 h[4]; uint2 u; } cv;
                cv.h[0] = __float2bfloat16(v.x); cv.h[1] = __float2bfloat16(v.y);
                cv.h[2] = __float2bfloat16(v.z); cv.h[3] = __float2bfloat16(v.w);
                *(uint2*)(xb + (size_t)(tok0 + row) * D_ + kc + col) = cv.u;
            }
            // stage W chunk [128 k][16 c] skewed; cols 0-7 = Wr, 8-15 = Wn
            {
                const float* src = (wh ? Wn : Wr) + (size_t)(kc + wk) * E_;
                const f32x4 w0 = *(const f32x4*)(src);
                const f32x4 w1 = *(const f32x4*)(src + 4);
                float* dst = wsh + wk * 16 + (wk >> 3) * 4 + wh * 8;
                *(f32x4*)(dst)     = w0;
                *(f32x4*)(dst + 4) = w1;
            }
            __syncthreads();

            // compute: this lane's 8 k-values of the chunk (k = kidx*8 + kk)
            const float* xra = xs + tl * XS_STRIDE + kidx * 8;
            const f32x4 xa0 = *(const f32x4*)(xra);
            const f32x4 xa1 = *(const f32x4*)(xra + 4);
            const float* wbase = wsh + kidx * 132;  // (kidx*8)*16 + kidx*4
            #pragma unroll
            for (int kk = 0; kk < 8; ++kk) {
                const float xav = (kk < 4) ? xa0[kk] : xa1[kk - 4];
                const float* wrow = wbase + kk * 16;
                #pragma unroll
                for (int c4 = 0; c4 < 4; ++c4) {
                    const f32x4 w = *(const f32x4*)(wrow + c4 * 4);
                    #pragma unroll
                    for (int c = 0; c < 4; ++c)
                        acc[c4 * 4 + c] = fmaf(xav, w[c], acc[c4 * 4 + c]);
                }
            }
            __syncthreads();
        }

        // reduce across the 16 kidx lanes (stride 4): xor 4,8,16,32
        #pragma unroll
        for (int off = 4; off < 64; off <<= 1) {
            #pragma unroll
            for (int c = 0; c < 16; ++c)
                acc[c] += __shfl_xor(acc[c], off);
        }

        if (lane < 4) {  // kidx==0 lanes hold full dots for token tl
            const int tok = tok0 + tl;
            float nv[8];
            #pragma unroll
            for (int e = 0; e < 8; ++e) {
                const float nl = acc[8 + e] + bn[e];
                // jax.nn.softplus = max(z,0) + log1p(exp(-|z|))
                const float sp = fmaxf(nl, 0.f) + log1pf(expf(-fabsf(nl)));
                nv[e] = acc[e] + br[e] + eps[(size_t)tok * E_ + e] * sp;
            }
            // top-2, lax.top_k tie semantics (lowest index wins ties)
            int i1 = 0; float v1 = nv[0];
            #pragma unroll
            for (int e = 1; e < 8; ++e)
                if (nv[e] > v1) { v1 = nv[e]; i1 = e; }
            int i2 = -1; float v2 = -3.4e38f;
            #pragma unroll
            for (int e = 0; e < 8; ++e)
                if (e != i1 && nv[e] > v2) { v2 = nv[e]; i2 = e; }
            const float t  = expf(v2 - v1);
            const float g1 = 1.f / (1.f + t);
            const float g2 = t / (1.f + t);
            // fused bucket: direct pair atomic + entry write
            const int aa = min(i1, i2), bb = max(i1, i2);
            const float gae = (i1 < i2) ? g1 : g2;   // gate of expert aa
            const float gbe = (i1 < i2) ? g2 : g1;   // gate of expert bb
            const int p = aa * (15 - aa) / 2 + (bb - aa - 1);
            const int slot = atomicAdd(&counts[p], 1);
            entries[(size_t)p * CAP + slot] =
                make_uint4((unsigned)tok, __float_as_uint(gae),
                           __float_as_uint(gbe), 0u);
        }
    } else {
        // ------------------------ transpose body -----------------------
        const int idx = bid - PREP_ROUTER_BLOCKS;   // [0, 2048)
        const int e  = idx >> 8;
        const int rem = idx & 255;
        const int d0 = (rem & 15) * 32;
        const int h0 = (rem >> 4) * 32;
        const int tx = tid & 31, ty = tid >> 5;     // 32 x 8
        float (*tile)[33] = reinterpret_cast<float(*)[33]>(smem);

        const float* src = Wk + ((size_t)e * D_ + d0) * D_ + h0;
        #pragma unroll
        for (int r = ty; r < 32; r += 8)
            tile[r][tx] = src[(size_t)r * D_ + tx];
        __syncthreads();
        __hip_bfloat16* dst = wkt + ((size_t)e * D_ + h0) * D_ + d0;
        #pragma unroll
        for (int r = ty; r < 32; r += 8)
            dst[(size_t)r * D_ + tx] = __float2bfloat16(tile[tx][r]);
    }

    // ---------------- done-counter + worklist build (last block) -----------
    __threadfence();
    __syncthreads();
    if (tid == 0)
        lastBlock = (atomicAdd(done, 1) == PREP_BLOCKS - 1) ? 1 : 0;
    __syncthreads();
    if (lastBlock && tid < 64) {
        const int t = tid;  // single wave
        // device-scope read of counts (written by other blocks' atomics)
        const int c = (t < NPAIR) ? atomicAdd(&counts[t], 0) : 0;
        const int nm = (c + 127) >> 7;
        int inc = nm;  // inclusive prefix sum across the wave
        #pragma unroll
        for (int d = 1; d < 64; d <<= 1) {
            const int v = __shfl_up(inc, d);
            if (t >= d) inc += v;
        }
        if (t == 63) wl[0] = inc;           // total mtiles
        const int ex = inc - nm;            // exclusive prefix
        for (int m = 0; m < nm; ++m)
            wl[1 + ex + m] = (t << 8) | m;
    }
}

// ---------------------------------------------------------------------------
// Kernel 2: pair-grouped expert GEMM, DIRECT output.
//   R9 vs R8: occupancy 2 -> 3 blocks/CU. LDS 74 -> 50 KB (2 buffers) while
//   KEEPING depth-2 prefetch via the split K-step:
//     vmcnt(6) ; bar ; ds_read->regs ; lgkmcnt(0) ; bar ;
//     STAGE(t+2 -> just-read buffer) ; MFMA
//   12 waves/CU (3/SIMD) now interleave the vmcnt stalls that R8's 8 waves
//   could not cover (R1 occupancy counter: blocks spent ~4000cyc/K-step).
//   Keep: worklist grid + XCD decode, XOR chunk swizzle (src+read sides),
//   counted vmcnt (never 0 mid-loop), setprio around MFMA cluster.
// ---------------------------------------------------------------------------
__global__ __launch_bounds__(256, 3) void moe_gemm(
    const __hip_bfloat16* __restrict__ xb,   // [NTOK][D] bf16
    const __hip_bfloat16* __restrict__ wkt,  // [E][D(out)][D(in)] bf16 (B^T)
    const float* __restrict__ bk,            // [E][D]
    const int* __restrict__ counts,          // [NPAIR]
    const uint4* __restrict__ entries,       // [NPAIR][CAP]
    const int* __restrict__ wl,              // [1+WL_MAX]
    float* __restrict__ out)                 // [NTOK][D] fp32 (fully written)
{
    constexpr int BM = 128, BN = 128, BK = 32;
    constexpr int NT = D_ / BK;  // 16 K-steps
    // row-major [row][BK] tiles; slot s of row r holds global chunk s^f(r),
    // f(r) = (r>>1)&3  (involution via XOR)
    __shared__ __hip_bfloat16 As[2][BM * BK];       // 2 x 8 KB
    __shared__ __hip_bfloat16 Bs[2][2][BN * BK];    // 2 x 16 KB
    __shared__ uint4 ent[BM];                       // 2 KB   (total 50 KB)

    // id = g*32 + nt*8 + j ; mtile = g*8 + j ; XCD = id%8 = j for all 4 nt
    const int id = blockIdx.x;
    const int g = id >> 5, r = id & 31;
    const int nt = r >> 3;
    const int mi = g * 8 + (r & 7);
    const int nmtot = wl[0];
    if (mi >= nmtot) return;
    const int we = wl[1 + mi];
    const int p = we >> 8, mt = we & 255;
    const int cnt = counts[p];

    // decode pair p -> (e1 < e2)
    int e1 = 0, rem = p;
    while (rem >= 7 - e1) { rem -= 7 - e1; ++e1; }
    const int e2 = e1 + 1 + rem;

    const int tid = threadIdx.x;
    const int wave = tid >> 6, lane = tid & 63;

    if (tid < BM) {
        const int idx = mt * BM + tid;
        ent[tid] = (idx < cnt) ? entries[(size_t)p * CAP + idx]
                               : make_uint4(0u, 0u, 0u, 0u);
    }
    __syncthreads();

    const int quad = lane >> 4, lr = lane & 15;
    const int wm = wave >> 1, wn = wave & 1;

    // --- staging geometry (64B contiguous per row, 16 rows per wave-call) ---
    // lane -> (row16 = lane>>2, chunk c = (lane&3) ^ f(row)); f telescopes to
    // (lane>>3)&3 because row = wave*32 + (lane>>2) and wave*32>>1 is mult of 16.
    const int r16 = lane >> 2;
    const int csel = (lane & 3) ^ ((lane >> 3) & 3);   // swizzled 16B chunk
    const int rA0 = wave * 32 + r16;                   // rows [w*32, w*32+16)
    const size_t tA0 = ent[rA0].x;
    const size_t tA1 = ent[rA0 + 16].x;
    const __hip_bfloat16* gA0 = xb + tA0 * D_ + csel * 8;
    const __hip_bfloat16* gA1 = xb + tA1 * D_ + csel * 8;
    const __hip_bfloat16* gB1 = wkt + ((size_t)e1 * D_ + nt * BN + rA0) * D_ + csel * 8;
    const __hip_bfloat16* gB2 = wkt + ((size_t)e2 * D_ + nt * BN + rA0) * D_ + csel * 8;

    // read-side swizzled slot (per-lane constant): quad ^ ((lr>>1)&3)
    const int so = (quad ^ ((lr >> 1) & 3)) * 8;

    f32x4 accA[4][4], accB[4][4];
    #pragma unroll
    for (int i = 0; i < 4; ++i)
        #pragma unroll
        for (int j = 0; j < 4; ++j) {
            accA[i][j] = (f32x4){0.f, 0.f, 0.f, 0.f};
            accB[i][j] = (f32x4){0.f, 0.f, 0.f, 0.f};
        }

    // 6 async loads per wave per STAGE -> vmcnt counts in units of 6
#define STAGE(buf, k0) do {                                        \
        __hip_bfloat16* aB  = &As[buf][wave * 1024];               \
        __hip_bfloat16* b1B = &Bs[buf][0][wave * 1024];            \
        __hip_bfloat16* b2B = &Bs[buf][1][wave * 1024];            \
        async_load16(gA0 + (k0), aB);                              \
        async_load16(gA1 + (k0), aB + 512);                        \
        async_load16(gB1 + (k0), b1B);                             \
        async_load16(gB1 + 16 * D_ + (k0), b1B + 512);             \
        async_load16(gB2 + (k0), b2B);                             \
        async_load16(gB2 + 16 * D_ + (k0), b2B + 512);             \
    } while (0)

#define READS(buf) do {                                                        \
        _Pragma("unroll")                                                      \
        for (int i = 0; i < 4; ++i)                                            \
            a[i] = *(const short8*)(&As[buf][(wm * 64 + i * 16 + lr) * 32 + so]); \
        _Pragma("unroll")                                                      \
        for (int j = 0; j < 4; ++j) {                                          \
            b1v[j] = *(const short8*)(&Bs[buf][0][(wn * 64 + j * 16 + lr) * 32 + so]); \
            b2v[j] = *(const short8*)(&Bs[buf][1][(wn * 64 + j * 16 + lr) * 32 + so]); \
        }                                                                      \
    } while (0)

#define MFMAS() do {                                                           \
        __builtin_amdgcn_s_setprio(1);                                         \
        _Pragma("unroll")                                                      \
        for (int i = 0; i < 4; ++i)                                            \
            _Pragma("unroll")                                                  \
            for (int j = 0; j < 4; ++j) {                                      \
                accA[i][j] = __builtin_amdgcn_mfma_f32_16x16x32_bf16(          \
                    a[i], b1v[j], accA[i][j], 0, 0, 0);                        \
                accB[i][j] = __builtin_amdgcn_mfma_f32_16x16x32_bf16(          \
                    a[i], b2v[j], accB[i][j], 0, 0, 0);                        \
            }                                                                  \
        __builtin_amdgcn_s_setprio(0);                                         \
    } while (0)

    // prologue: tiles 0 and 1 in flight (12 outstanding VMEM ops per wave)
    STAGE(0, 0);
    STAGE(1, BK);

    // steady state (split K-step): tile t lands -> read to regs -> drain
    // lgkm -> barrier -> refill the SAME buffer with tile t+2 -> MFMA.
    for (int t = 0; t < NT - 1; ++t) {
        short8 a[4], b1v[4], b2v[4];
        asm volatile("s_waitcnt vmcnt(6)" ::: "memory");
        __builtin_amdgcn_s_barrier();
        READS(t & 1);
        asm volatile("s_waitcnt lgkmcnt(0)" ::: "memory");
        __builtin_amdgcn_s_barrier();
        if (t + 2 < NT) STAGE(t & 1, (t + 2) * BK);
        MFMAS();
    }
    {
        short8 a[4], b1v[4], b2v[4];
        asm volatile("s_waitcnt vmcnt(0)" ::: "memory");
        __builtin_amdgcn_s_barrier();
        READS((NT - 1) & 1);
        MFMAS();
    }

#undef STAGE
#undef READS
#undef MFMAS

    const int colbase = nt * BN + wn * 64 + lr;
    float bkA[4], bkB[4];
    #pragma unroll
    for (int j = 0; j < 4; ++j) {
        bkA[j] = bk[e1 * D_ + colbase + j * 16];
        bkB[j] = bk[e2 * D_ + colbase + j * 16];
    }

    #pragma unroll
    for (int i = 0; i < 4; ++i) {
        #pragma unroll
        for (int rr = 0; rr < 4; ++rr) {
            const int row = wm * 64 + i * 16 + quad * 4 + rr;  // C: row = quad*4+reg
            if (mt * BM + row < cnt) {
                const uint4 en = ent[row];
                const float ga = __uint_as_float(en.y);
                const float gb = __uint_as_float(en.z);
                float* orow = out + (size_t)en.x * D_ + colbase;
                #pragma unroll
                for (int j = 0; j < 4; ++j)
                    orow[j * 16] = ga * (accA[i][j][rr] + bkA[j])
                                 + gb * (accB[i][j][rr] + bkB[j]);
            }
        }
    }
}

// ---------------------------------------------------------------------------
// Launch: 3 dispatches (was 6): memset, fused prep, gemm.
// ---------------------------------------------------------------------------
extern "C" void kernel_launch(void* const* d_in, const int* in_sizes, int n_in,
                              void* d_out, int out_size, void* d_ws, size_t ws_size,
                              hipStream_t stream) {
    const float* x   = (const float*)d_in[0];
    const float* eps = (const float*)d_in[1];
    const float* Wr  = (const float*)d_in[2];
    const float* br  = (const float*)d_in[3];
    const float* Wn  = (const float*)d_in[4];
    const float* bn  = (const float*)d_in[5];
    const float* Wk  = (const float*)d_in[6];
    const float* bk  = (const float*)d_in[7];
    float* out = (float*)d_out;

    // workspace layout (256B-aligned): ~28 MB total
    char* ws = (char*)d_ws;
    size_t off = 0;
    int* counts = (int*)(ws + off);                     off += 256;   // counts[28] + done @int32
    uint4* entries = (uint4*)(ws + off);                off += (size_t)NPAIR * CAP * 16;  // 7.3 MiB
    __hip_bfloat16* xb = (__hip_bfloat16*)(ws + off);   off += (size_t)NTOK * D_ * 2;     // 16 MiB
    __hip_bfloat16* wkt = (__hip_bfloat16*)(ws + off);  off += (size_t)E_ * D_ * D_ * 2;  // 4 MiB
    int* wl = (int*)(ws + off);                         off += 1024;                      // worklist
    int* done = counts + 32;   // byte offset 128, inside the memset'd 256 B
    (void)ws_size;

    hipMemsetAsync(counts, 0, 256, stream);   // zeroes counts[] and done

    prep_kernel<<<dim3(PREP_BLOCKS), dim3(256), 0, stream>>>(
        x, eps, Wr, br, Wn, bn, Wk, xb, wkt, counts, entries, done, wl);
    moe_gemm<<<dim3(WL_MAX * 4), dim3(256), 0, stream>>>(
        xb, wkt, bk, counts, entries, wl, out);
}

// Round 4
// 292.553 us; speedup vs baseline: 1.6252x; 1.6252x over previous
//
#include <hip/hip_runtime.h>
#include <hip/hip_bf16.h>
#include <math.h>

// Problem constants
#define B_    8
#define T_    2048
#define NTOK  (B_ * T_)   // 16384 tokens
#define D_    512
#define E_    8
#define NPAIR 28          // unordered expert pairs (top-2 always distinct)
#define CAP   NTOK        // per-pair bucket capacity (worst case)
#define CPAD  32          // counts padding: one counter per 128B line

// worklist: wl[0] = total mtiles; wl[1+i] = (pair<<8)|mtile.
// Sum ceil(cnt_p/128) <= 128 + 27 = 155 -> pad to 160 (multiple of 8 for XCD map)
#define WL_MAX 160

// router: 1024 blocks x 256 thr; 16 tok/block, 4 tok/wave.
#define RV_TOK    16
#define RV_THR    256
#define XS_STRIDE 132
#define WS_FLOATS 2108

// fused prep kernel: router blocks + transpose blocks
#define PREP_ROUTER_BLOCKS (NTOK / RV_TOK)        // 1024
#define PREP_TRANS_BLOCKS  (16 * 16 * E_)          // 2048
#define PREP_BLOCKS (PREP_ROUTER_BLOCKS + PREP_TRANS_BLOCKS)  // 3072

typedef __attribute__((ext_vector_type(4))) float f32x4;
typedef __attribute__((ext_vector_type(8))) short short8;  // 8 bf16 (MFMA a/b frag)

__device__ __forceinline__ void async_load16(const void* g, void* l) {
    __builtin_amdgcn_global_load_lds(
        (const __attribute__((address_space(1))) unsigned int*)g,
        (__attribute__((address_space(3))) unsigned int*)l,
        16, 0, 0);
}

// ---------------------------------------------------------------------------
// Kernel 1 (fused prep): transpose_wk  U  router+bucket  U  build_wl.
//   R4 fix vs R3 (343us atomic storm): per-token device atomics (16384 ops
//   into ONE cacheline, ~50cy each serialized = the whole 343us) replaced by
//   bucket_kernel's two-level scheme INSIDE the fused block: LDS hist ->
//   <=16 global atomics/block onto line-padded counters (counts[p*CPAD]).
//   __threadfence(): was per-thread (786K device-scope fences); now tid0-only
//   after __syncthreads (which already drains vmcnt -> atomics acked/visible).
// ---------------------------------------------------------------------------
__global__ __launch_bounds__(256) void prep_kernel(
    const float* __restrict__ x,     // [NTOK][D]
    const float* __restrict__ eps,   // [NTOK][E]
    const float* __restrict__ Wr,    // [D][E]
    const float* __restrict__ br,    // [E]
    const float* __restrict__ Wn,    // [D][E]
    const float* __restrict__ bn,    // [E]
    const float* __restrict__ Wk,    // [E][D][D]
    __hip_bfloat16* __restrict__ xb,   // out: [NTOK][D] bf16
    __hip_bfloat16* __restrict__ wkt,  // out: [E][D][D] bf16 (B^T)
    int* __restrict__ counts,          // [NPAIR*CPAD] pre-zeroed (line-padded)
    uint4* __restrict__ entries,       // [NPAIR][CAP]
    int* __restrict__ done,            // pre-zeroed
    int* __restrict__ wl)              // [1+WL_MAX]
{
    __shared__ float smem[RV_TOK * XS_STRIDE + WS_FLOATS];  // 16.9 KB
    __shared__ int hist[NPAIR];
    __shared__ int basep[NPAIR];
    __shared__ int lastBlock;
    const int bid = blockIdx.x, tid = threadIdx.x;

    if (bid < PREP_ROUTER_BLOCKS) {
        // ------------------------- router body -------------------------
        float* xs  = smem;                         // [RV_TOK][XS_STRIDE]
        float* wsh = smem + RV_TOK * XS_STRIDE;    // skewed [128][16]

        const int tok0 = bid * RV_TOK;
        const int lane = tid & 63, wv = tid >> 6;
        const int kidx = lane >> 2, ts = lane & 3;
        const int tl = wv * 4 + ts;                // this lane's token
        const int wk = tid >> 1, wh = tid & 1;     // W stager: row, half

        if (tid < NPAIR) hist[tid] = 0;

        float acc[16];  // [0..7]=x.Wr per expert, [8..15]=x.Wn
        #pragma unroll
        for (int c = 0; c < 16; ++c) acc[c] = 0.f;

        for (int kc = 0; kc < D_; kc += 128) {
            // stage x chunk [16 tok][128 k] + fused bf16 convert/store
            #pragma unroll
            for (int it = 0; it < 2; ++it) {
                const int f   = it * RV_THR + tid;      // f32x4 index in [0,512)
                const int row = f >> 5, col = (f & 31) * 4;
                const f32x4 v = *(const f32x4*)(x + (size_t)(tok0 + row) * D_ + kc + col);
                *(f32x4*)(xs + row * XS_STRIDE + col) = v;
                union { __hip_bfloat16 h[4]; uint2 u; } cv;
                cv.h[0] = __float2bfloat16(v.x); cv.h[1] = __float2bfloat16(v.y);
                cv.h[2] = __float2bfloat16(v.z); cv.h[3] = __float2bfloat16(v.w);
                *(uint2*)(xb + (size_t)(tok0 + row) * D_ + kc + col) = cv.u;
            }
            // stage W chunk [128 k][16 c] skewed; cols 0-7 = Wr, 8-15 = Wn
            {
                const float* src = (wh ? Wn : Wr) + (size_t)(kc + wk) * E_;
                const f32x4 w0 = *(const f32x4*)(src);
                const f32x4 w1 = *(const f32x4*)(src + 4);
                float* dst = wsh + wk * 16 + (wk >> 3) * 4 + wh * 8;
                *(f32x4*)(dst)     = w0;
                *(f32x4*)(dst + 4) = w1;
            }
            __syncthreads();

            // compute: this lane's 8 k-values of the chunk (k = kidx*8 + kk)
            const float* xra = xs + tl * XS_STRIDE + kidx * 8;
            const f32x4 xa0 = *(const f32x4*)(xra);
            const f32x4 xa1 = *(const f32x4*)(xra + 4);
            const float* wbase = wsh + kidx * 132;  // (kidx*8)*16 + kidx*4
            #pragma unroll
            for (int kk = 0; kk < 8; ++kk) {
                const float xav = (kk < 4) ? xa0[kk] : xa1[kk - 4];
                const float* wrow = wbase + kk * 16;
                #pragma unroll
                for (int c4 = 0; c4 < 4; ++c4) {
                    const f32x4 w = *(const f32x4*)(wrow + c4 * 4);
                    #pragma unroll
                    for (int c = 0; c < 4; ++c)
                        acc[c4 * 4 + c] = fmaf(xav, w[c], acc[c4 * 4 + c]);
                }
            }
            __syncthreads();
        }

        // reduce across the 16 kidx lanes (stride 4): xor 4,8,16,32
        #pragma unroll
        for (int off = 4; off < 64; off <<= 1) {
            #pragma unroll
            for (int c = 0; c < 16; ++c)
                acc[c] += __shfl_xor(acc[c], off);
        }

        // ---- top-2 + two-level bucket (LDS hist -> padded global atomics) ----
        int p_ = 0, l_ = 0, tok_ = 0;
        float gae_ = 0.f, gbe_ = 0.f;
        const bool writer = (lane < 4);
        if (writer) {  // kidx==0 lanes hold full dots for token tl
            tok_ = tok0 + tl;
            float nv[8];
            #pragma unroll
            for (int e = 0; e < 8; ++e) {
                const float nl = acc[8 + e] + bn[e];
                // jax.nn.softplus = max(z,0) + log1p(exp(-|z|))
                const float sp = fmaxf(nl, 0.f) + log1pf(expf(-fabsf(nl)));
                nv[e] = acc[e] + br[e] + eps[(size_t)tok_ * E_ + e] * sp;
            }
            // top-2, lax.top_k tie semantics (lowest index wins ties)
            int i1 = 0; float v1 = nv[0];
            #pragma unroll
            for (int e = 1; e < 8; ++e)
                if (nv[e] > v1) { v1 = nv[e]; i1 = e; }
            int i2 = -1; float v2 = -3.4e38f;
            #pragma unroll
            for (int e = 0; e < 8; ++e)
                if (e != i1 && nv[e] > v2) { v2 = nv[e]; i2 = e; }
            const float t  = expf(v2 - v1);
            const float g1 = 1.f / (1.f + t);
            const float g2 = t / (1.f + t);
            const int aa = min(i1, i2), bb = max(i1, i2);
            gae_ = (i1 < i2) ? g1 : g2;   // gate of expert aa
            gbe_ = (i1 < i2) ? g2 : g1;   // gate of expert bb
            p_ = aa * (15 - aa) / 2 + (bb - aa - 1);
            l_ = atomicAdd(&hist[p_], 1);            // LDS atomic (cheap)
        }
        __syncthreads();
        if (tid < NPAIR && hist[tid] > 0)
            basep[tid] = atomicAdd(counts + tid * CPAD, hist[tid]);  // own line
        __syncthreads();
        if (writer)
            entries[(size_t)p_ * CAP + basep[p_] + l_] =
                make_uint4((unsigned)tok_, __float_as_uint(gae_),
                           __float_as_uint(gbe_), 0u);
    } else {
        // ------------------------ transpose body -----------------------
        const int idx = bid - PREP_ROUTER_BLOCKS;   // [0, 2048)
        const int e  = idx >> 8;
        const int rem = idx & 255;
        const int d0 = (rem & 15) * 32;
        const int h0 = (rem >> 4) * 32;
        const int tx = tid & 31, ty = tid >> 5;     // 32 x 8
        float (*tile)[33] = reinterpret_cast<float(*)[33]>(smem);

        const float* src = Wk + ((size_t)e * D_ + d0) * D_ + h0;
        #pragma unroll
        for (int r = ty; r < 32; r += 8)
            tile[r][tx] = src[(size_t)r * D_ + tx];
        __syncthreads();
        __hip_bfloat16* dst = wkt + ((size_t)e * D_ + h0) * D_ + d0;
        #pragma unroll
        for (int r = ty; r < 32; r += 8)
            dst[(size_t)r * D_ + tx] = __float2bfloat16(tile[tx][r]);
    }

    // ---------------- done-counter + worklist build (last block) -----------
    // __syncthreads drains vmcnt(0): this block's counts-atomics are acked at
    // the coherence point (globally visible). tid0-only fence, then signal.
    __syncthreads();
    if (tid == 0) {
        __threadfence();
        lastBlock = (atomicAdd(done, 1) == PREP_BLOCKS - 1) ? 1 : 0;
    }
    __syncthreads();
    if (lastBlock && tid < 64) {
        const int t = tid;  // single wave
        // device-scope read of counts (written by other blocks' atomics)
        const int c = (t < NPAIR) ? atomicAdd(counts + t * CPAD, 0) : 0;
        const int nm = (c + 127) >> 7;
        int inc = nm;  // inclusive prefix sum across the wave
        #pragma unroll
        for (int d = 1; d < 64; d <<= 1) {
            const int v = __shfl_up(inc, d);
            if (t >= d) inc += v;
        }
        if (t == 63) wl[0] = inc;           // total mtiles
        const int ex = inc - nm;            // exclusive prefix
        for (int m = 0; m < nm; ++m)
            wl[1 + ex + m] = (t << 8) | m;
    }
}

// ---------------------------------------------------------------------------
// Kernel 2: pair-grouped expert GEMM, DIRECT output. (Unchanged from R3
// except counts is now line-padded: counts[p*CPAD].)
//   Split K-step, 2 LDS buffers, depth-2 prefetch, 3 blocks/CU:
//     vmcnt(6) ; bar ; ds_read->regs ; lgkmcnt(0) ; bar ;
//     STAGE(t+2 -> just-read buffer) ; MFMA
//   Worklist grid + XCD decode, XOR chunk swizzle (src+read), counted vmcnt,
//   setprio around MFMA cluster.
// ---------------------------------------------------------------------------
__global__ __launch_bounds__(256, 3) void moe_gemm(
    const __hip_bfloat16* __restrict__ xb,   // [NTOK][D] bf16
    const __hip_bfloat16* __restrict__ wkt,  // [E][D(out)][D(in)] bf16 (B^T)
    const float* __restrict__ bk,            // [E][D]
    const int* __restrict__ counts,          // [NPAIR*CPAD] line-padded
    const uint4* __restrict__ entries,       // [NPAIR][CAP]
    const int* __restrict__ wl,              // [1+WL_MAX]
    float* __restrict__ out)                 // [NTOK][D] fp32 (fully written)
{
    constexpr int BM = 128, BN = 128, BK = 32;
    constexpr int NT = D_ / BK;  // 16 K-steps
    // row-major [row][BK] tiles; slot s of row r holds global chunk s^f(r),
    // f(r) = (r>>1)&3  (involution via XOR)
    __shared__ __hip_bfloat16 As[2][BM * BK];       // 2 x 8 KB
    __shared__ __hip_bfloat16 Bs[2][2][BN * BK];    // 2 x 16 KB
    __shared__ uint4 ent[BM];                       // 2 KB   (total 50 KB)

    // id = g*32 + nt*8 + j ; mtile = g*8 + j ; XCD = id%8 = j for all 4 nt
    const int id = blockIdx.x;
    const int g = id >> 5, r = id & 31;
    const int nt = r >> 3;
    const int mi = g * 8 + (r & 7);
    const int nmtot = wl[0];
    if (mi >= nmtot) return;
    const int we = wl[1 + mi];
    const int p = we >> 8, mt = we & 255;
    const int cnt = counts[p * CPAD];

    // decode pair p -> (e1 < e2)
    int e1 = 0, rem = p;
    while (rem >= 7 - e1) { rem -= 7 - e1; ++e1; }
    const int e2 = e1 + 1 + rem;

    const int tid = threadIdx.x;
    const int wave = tid >> 6, lane = tid & 63;

    if (tid < BM) {
        const int idx = mt * BM + tid;
        ent[tid] = (idx < cnt) ? entries[(size_t)p * CAP + idx]
                               : make_uint4(0u, 0u, 0u, 0u);
    }
    __syncthreads();

    const int quad = lane >> 4, lr = lane & 15;
    const int wm = wave >> 1, wn = wave & 1;

    // --- staging geometry (64B contiguous per row, 16 rows per wave-call) ---
    // lane -> (row16 = lane>>2, chunk c = (lane&3) ^ f(row)); f telescopes to
    // (lane>>3)&3 because row = wave*32 + (lane>>2) and wave*32>>1 is mult of 16.
    const int r16 = lane >> 2;
    const int csel = (lane & 3) ^ ((lane >> 3) & 3);   // swizzled 16B chunk
    const int rA0 = wave * 32 + r16;                   // rows [w*32, w*32+16)
    const size_t tA0 = ent[rA0].x;
    const size_t tA1 = ent[rA0 + 16].x;
    const __hip_bfloat16* gA0 = xb + tA0 * D_ + csel * 8;
    const __hip_bfloat16* gA1 = xb + tA1 * D_ + csel * 8;
    const __hip_bfloat16* gB1 = wkt + ((size_t)e1 * D_ + nt * BN + rA0) * D_ + csel * 8;
    const __hip_bfloat16* gB2 = wkt + ((size_t)e2 * D_ + nt * BN + rA0) * D_ + csel * 8;

    // read-side swizzled slot (per-lane constant): quad ^ ((lr>>1)&3)
    const int so = (quad ^ ((lr >> 1) & 3)) * 8;

    f32x4 accA[4][4], accB[4][4];
    #pragma unroll
    for (int i = 0; i < 4; ++i)
        #pragma unroll
        for (int j = 0; j < 4; ++j) {
            accA[i][j] = (f32x4){0.f, 0.f, 0.f, 0.f};
            accB[i][j] = (f32x4){0.f, 0.f, 0.f, 0.f};
        }

    // 6 async loads per wave per STAGE -> vmcnt counts in units of 6
#define STAGE(buf, k0) do {                                        \
        __hip_bfloat16* aB  = &As[buf][wave * 1024];               \
        __hip_bfloat16* b1B = &Bs[buf][0][wave * 1024];            \
        __hip_bfloat16* b2B = &Bs[buf][1][wave * 1024];            \
        async_load16(gA0 + (k0), aB);                              \
        async_load16(gA1 + (k0), aB + 512);                        \
        async_load16(gB1 + (k0), b1B);                             \
        async_load16(gB1 + 16 * D_ + (k0), b1B + 512);             \
        async_load16(gB2 + (k0), b2B);                             \
        async_load16(gB2 + 16 * D_ + (k0), b2B + 512);             \
    } while (0)

#define READS(buf) do {                                                        \
        _Pragma("unroll")                                                      \
        for (int i = 0; i < 4; ++i)                                            \
            a[i] = *(const short8*)(&As[buf][(wm * 64 + i * 16 + lr) * 32 + so]); \
        _Pragma("unroll")                                                      \
        for (int j = 0; j < 4; ++j) {                                          \
            b1v[j] = *(const short8*)(&Bs[buf][0][(wn * 64 + j * 16 + lr) * 32 + so]); \
            b2v[j] = *(const short8*)(&Bs[buf][1][(wn * 64 + j * 16 + lr) * 32 + so]); \
        }                                                                      \
    } while (0)

#define MFMAS() do {                                                           \
        __builtin_amdgcn_s_setprio(1);                                         \
        _Pragma("unroll")                                                      \
        for (int i = 0; i < 4; ++i)                                            \
            _Pragma("unroll")                                                  \
            for (int j = 0; j < 4; ++j) {                                      \
                accA[i][j] = __builtin_amdgcn_mfma_f32_16x16x32_bf16(          \
                    a[i], b1v[j], accA[i][j], 0, 0, 0);                        \
                accB[i][j] = __builtin_amdgcn_mfma_f32_16x16x32_bf16(          \
                    a[i], b2v[j], accB[i][j], 0, 0, 0);                        \
            }                                                                  \
        __builtin_amdgcn_s_setprio(0);                                         \
    } while (0)

    // prologue: tiles 0 and 1 in flight (12 outstanding VMEM ops per wave)
    STAGE(0, 0);
    STAGE(1, BK);

    // steady state (split K-step): tile t lands -> read to regs -> drain
    // lgkm -> barrier -> refill the SAME buffer with tile t+2 -> MFMA.
    for (int t = 0; t < NT - 1; ++t) {
        short8 a[4], b1v[4], b2v[4];
        asm volatile("s_waitcnt vmcnt(6)" ::: "memory");
        __builtin_amdgcn_s_barrier();
        READS(t & 1);
        asm volatile("s_waitcnt lgkmcnt(0)" ::: "memory");
        __builtin_amdgcn_s_barrier();
        if (t + 2 < NT) STAGE(t & 1, (t + 2) * BK);
        MFMAS();
    }
    {
        short8 a[4], b1v[4], b2v[4];
        asm volatile("s_waitcnt vmcnt(0)" ::: "memory");
        __builtin_amdgcn_s_barrier();
        READS((NT - 1) & 1);
        MFMAS();
    }

#undef STAGE
#undef READS
#undef MFMAS

    const int colbase = nt * BN + wn * 64 + lr;
    float bkA[4], bkB[4];
    #pragma unroll
    for (int j = 0; j < 4; ++j) {
        bkA[j] = bk[e1 * D_ + colbase + j * 16];
        bkB[j] = bk[e2 * D_ + colbase + j * 16];
    }

    #pragma unroll
    for (int i = 0; i < 4; ++i) {
        #pragma unroll
        for (int rr = 0; rr < 4; ++rr) {
            const int row = wm * 64 + i * 16 + quad * 4 + rr;  // C: row = quad*4+reg
            if (mt * BM + row < cnt) {
                const uint4 en = ent[row];
                const float ga = __uint_as_float(en.y);
                const float gb = __uint_as_float(en.z);
                float* orow = out + (size_t)en.x * D_ + colbase;
                #pragma unroll
                for (int j = 0; j < 4; ++j)
                    orow[j * 16] = ga * (accA[i][j][rr] + bkA[j])
                                 + gb * (accB[i][j][rr] + bkB[j]);
            }
        }
    }
}

// ---------------------------------------------------------------------------
// Launch: 3 dispatches: memset, fused prep, gemm.
// ---------------------------------------------------------------------------
extern "C" void kernel_launch(void* const* d_in, const int* in_sizes, int n_in,
                              void* d_out, int out_size, void* d_ws, size_t ws_size,
                              hipStream_t stream) {
    const float* x   = (const float*)d_in[0];
    const float* eps = (const float*)d_in[1];
    const float* Wr  = (const float*)d_in[2];
    const float* br  = (const float*)d_in[3];
    const float* Wn  = (const float*)d_in[4];
    const float* bn  = (const float*)d_in[5];
    const float* Wk  = (const float*)d_in[6];
    const float* bk  = (const float*)d_in[7];
    float* out = (float*)d_out;

    // workspace layout (256B-aligned): ~28 MB total
    char* ws = (char*)d_ws;
    size_t off = 0;
    int* counts = (int*)(ws + off);                     off += 8192;  // NPAIR*CPAD ints (3.5KB) + done, padded
    uint4* entries = (uint4*)(ws + off);                off += (size_t)NPAIR * CAP * 16;  // 7.3 MiB
    __hip_bfloat16* xb = (__hip_bfloat16*)(ws + off);   off += (size_t)NTOK * D_ * 2;     // 16 MiB
    __hip_bfloat16* wkt = (__hip_bfloat16*)(ws + off);  off += (size_t)E_ * D_ * D_ * 2;  // 4 MiB
    int* wl = (int*)(ws + off);                         off += 1024;                      // worklist
    int* done = counts + NPAIR * CPAD;   // offset 3584B, inside memset'd region
    (void)ws_size;

    hipMemsetAsync(counts, 0, 8192, stream);   // zeroes counts[] and done

    prep_kernel<<<dim3(PREP_BLOCKS), dim3(256), 0, stream>>>(
        x, eps, Wr, br, Wn, bn, Wk, xb, wkt, counts, entries, done, wl);
    moe_gemm<<<dim3(WL_MAX * 4), dim3(256), 0, stream>>>(
        xb, wkt, bk, counts, entries, wl, out);
}

// Round 5
// 208.817 us; speedup vs baseline: 2.2768x; 1.4010x over previous
//
#include <hip/hip_runtime.h>
#include <hip/hip_bf16.h>
#include <math.h>

// Problem constants
#define B_    8
#define T_    2048
#define NTOK  (B_ * T_)   // 16384 tokens
#define D_    512
#define E_    8
#define NPAIR 28          // unordered expert pairs (top-2 always distinct)
#define CAP   NTOK        // per-pair bucket capacity (worst case)
#define CPAD  32          // counts padding: one counter per 128B line

// worklist: wl[0] = total mtiles; wl[1+i] = (pair<<8)|mtile.
// Sum ceil(cnt_p/128) <= 128 + 27 = 155 -> pad to 160 (multiple of 8 for XCD map)
#define WL_MAX 160

// router: 1024 blocks x 256 thr; 16 tok/block, 4 tok/wave.
#define RV_TOK    16
#define RV_THR    256
#define XS_STRIDE 132
#define WS_FLOATS 2108

// fused prep kernel: router blocks + transpose blocks
#define PREP_ROUTER_BLOCKS (NTOK / RV_TOK)        // 1024
#define PREP_TRANS_BLOCKS  (16 * 16 * E_)          // 2048
#define PREP_BLOCKS (PREP_ROUTER_BLOCKS + PREP_TRANS_BLOCKS)  // 3072

typedef __attribute__((ext_vector_type(4))) float f32x4;
typedef __attribute__((ext_vector_type(8))) short short8;  // 8 bf16 (MFMA a/b frag)

__device__ __forceinline__ void async_load16(const void* g, void* l) {
    __builtin_amdgcn_global_load_lds(
        (const __attribute__((address_space(1))) unsigned int*)g,
        (__attribute__((address_space(3))) unsigned int*)l,
        16, 0, 0);
}

// ---------------------------------------------------------------------------
// Kernel 1 (fused prep): transpose_wk  U  router(+bucket).
//   R5 fix vs R4 (130us): the per-block completion machinery (3072
//   same-line done-atomics ~21-30ns each serialized = 64-90us, plus 3072
//   device-scope __threadfence = repeated L2 writebacks) existed only to
//   build a 155-entry worklist in-kernel. Deleted entirely: no fence, no
//   done counter, no lastBlock. The worklist is built by a separate 1-wave
//   kernel (~2us, R2-measured); kernel boundaries provide visibility.
//   Prep is now a pure grid of independent blocks.
// ---------------------------------------------------------------------------
__global__ __launch_bounds__(256) void prep_kernel(
    const float* __restrict__ x,     // [NTOK][D]
    const float* __restrict__ eps,   // [NTOK][E]
    const float* __restrict__ Wr,    // [D][E]
    const float* __restrict__ br,    // [E]
    const float* __restrict__ Wn,    // [D][E]
    const float* __restrict__ bn,    // [E]
    const float* __restrict__ Wk,    // [E][D][D]
    __hip_bfloat16* __restrict__ xb,   // out: [NTOK][D] bf16
    __hip_bfloat16* __restrict__ wkt,  // out: [E][D][D] bf16 (B^T)
    int* __restrict__ counts,          // [NPAIR*CPAD] pre-zeroed (line-padded)
    uint4* __restrict__ entries)       // [NPAIR][CAP]
{
    __shared__ float smem[RV_TOK * XS_STRIDE + WS_FLOATS];  // 16.9 KB
    __shared__ int hist[NPAIR];
    __shared__ int basep[NPAIR];
    const int bid = blockIdx.x, tid = threadIdx.x;

    if (bid < PREP_ROUTER_BLOCKS) {
        // ------------------------- router body -------------------------
        float* xs  = smem;                         // [RV_TOK][XS_STRIDE]
        float* wsh = smem + RV_TOK * XS_STRIDE;    // skewed [128][16]

        const int tok0 = bid * RV_TOK;
        const int lane = tid & 63, wv = tid >> 6;
        const int kidx = lane >> 2, ts = lane & 3;
        const int tl = wv * 4 + ts;                // this lane's token
        const int wk = tid >> 1, wh = tid & 1;     // W stager: row, half

        if (tid < NPAIR) hist[tid] = 0;

        float acc[16];  // [0..7]=x.Wr per expert, [8..15]=x.Wn
        #pragma unroll
        for (int c = 0; c < 16; ++c) acc[c] = 0.f;

        for (int kc = 0; kc < D_; kc += 128) {
            // stage x chunk [16 tok][128 k] + fused bf16 convert/store
            #pragma unroll
            for (int it = 0; it < 2; ++it) {
                const int f   = it * RV_THR + tid;      // f32x4 index in [0,512)
                const int row = f >> 5, col = (f & 31) * 4;
                const f32x4 v = *(const f32x4*)(x + (size_t)(tok0 + row) * D_ + kc + col);
                *(f32x4*)(xs + row * XS_STRIDE + col) = v;
                union { __hip_bfloat16 h[4]; uint2 u; } cv;
                cv.h[0] = __float2bfloat16(v.x); cv.h[1] = __float2bfloat16(v.y);
                cv.h[2] = __float2bfloat16(v.z); cv.h[3] = __float2bfloat16(v.w);
                *(uint2*)(xb + (size_t)(tok0 + row) * D_ + kc + col) = cv.u;
            }
            // stage W chunk [128 k][16 c] skewed; cols 0-7 = Wr, 8-15 = Wn
            {
                const float* src = (wh ? Wn : Wr) + (size_t)(kc + wk) * E_;
                const f32x4 w0 = *(const f32x4*)(src);
                const f32x4 w1 = *(const f32x4*)(src + 4);
                float* dst = wsh + wk * 16 + (wk >> 3) * 4 + wh * 8;
                *(f32x4*)(dst)     = w0;
                *(f32x4*)(dst + 4) = w1;
            }
            __syncthreads();

            // compute: this lane's 8 k-values of the chunk (k = kidx*8 + kk)
            const float* xra = xs + tl * XS_STRIDE + kidx * 8;
            const f32x4 xa0 = *(const f32x4*)(xra);
            const f32x4 xa1 = *(const f32x4*)(xra + 4);
            const float* wbase = wsh + kidx * 132;  // (kidx*8)*16 + kidx*4
            #pragma unroll
            for (int kk = 0; kk < 8; ++kk) {
                const float xav = (kk < 4) ? xa0[kk] : xa1[kk - 4];
                const float* wrow = wbase + kk * 16;
                #pragma unroll
                for (int c4 = 0; c4 < 4; ++c4) {
                    const f32x4 w = *(const f32x4*)(wrow + c4 * 4);
                    #pragma unroll
                    for (int c = 0; c < 4; ++c)
                        acc[c4 * 4 + c] = fmaf(xav, w[c], acc[c4 * 4 + c]);
                }
            }
            __syncthreads();
        }

        // reduce across the 16 kidx lanes (stride 4): xor 4,8,16,32
        #pragma unroll
        for (int off = 4; off < 64; off <<= 1) {
            #pragma unroll
            for (int c = 0; c < 16; ++c)
                acc[c] += __shfl_xor(acc[c], off);
        }

        // ---- top-2 + two-level bucket (LDS hist -> padded global atomics) ----
        int p_ = 0, l_ = 0, tok_ = 0;
        float gae_ = 0.f, gbe_ = 0.f;
        const bool writer = (lane < 4);
        if (writer) {  // kidx==0 lanes hold full dots for token tl
            tok_ = tok0 + tl;
            float nv[8];
            #pragma unroll
            for (int e = 0; e < 8; ++e) {
                const float nl = acc[8 + e] + bn[e];
                // jax.nn.softplus = max(z,0) + log1p(exp(-|z|))
                const float sp = fmaxf(nl, 0.f) + log1pf(expf(-fabsf(nl)));
                nv[e] = acc[e] + br[e] + eps[(size_t)tok_ * E_ + e] * sp;
            }
            // top-2, lax.top_k tie semantics (lowest index wins ties)
            int i1 = 0; float v1 = nv[0];
            #pragma unroll
            for (int e = 1; e < 8; ++e)
                if (nv[e] > v1) { v1 = nv[e]; i1 = e; }
            int i2 = -1; float v2 = -3.4e38f;
            #pragma unroll
            for (int e = 0; e < 8; ++e)
                if (e != i1 && nv[e] > v2) { v2 = nv[e]; i2 = e; }
            const float t  = expf(v2 - v1);
            const float g1 = 1.f / (1.f + t);
            const float g2 = t / (1.f + t);
            const int aa = min(i1, i2), bb = max(i1, i2);
            gae_ = (i1 < i2) ? g1 : g2;   // gate of expert aa
            gbe_ = (i1 < i2) ? g2 : g1;   // gate of expert bb
            p_ = aa * (15 - aa) / 2 + (bb - aa - 1);
            l_ = atomicAdd(&hist[p_], 1);            // LDS atomic (cheap)
        }
        __syncthreads();
        if (tid < NPAIR && hist[tid] > 0)
            basep[tid] = atomicAdd(counts + tid * CPAD, hist[tid]);  // own line
        __syncthreads();
        if (writer)
            entries[(size_t)p_ * CAP + basep[p_] + l_] =
                make_uint4((unsigned)tok_, __float_as_uint(gae_),
                           __float_as_uint(gbe_), 0u);
    } else {
        // ------------------------ transpose body -----------------------
        const int idx = bid - PREP_ROUTER_BLOCKS;   // [0, 2048)
        const int e  = idx >> 8;
        const int rem = idx & 255;
        const int d0 = (rem & 15) * 32;
        const int h0 = (rem >> 4) * 32;
        const int tx = tid & 31, ty = tid >> 5;     // 32 x 8
        float (*tile)[33] = reinterpret_cast<float(*)[33]>(smem);

        const float* src = Wk + ((size_t)e * D_ + d0) * D_ + h0;
        #pragma unroll
        for (int r = ty; r < 32; r += 8)
            tile[r][tx] = src[(size_t)r * D_ + tx];
        __syncthreads();
        __hip_bfloat16* dst = wkt + ((size_t)e * D_ + h0) * D_ + d0;
        #pragma unroll
        for (int r = ty; r < 32; r += 8)
            dst[(size_t)r * D_ + tx] = __float2bfloat16(tile[tx][r]);
    }
    // (no fence, no done-counter: kernel boundary publishes everything)
}

// ---------------------------------------------------------------------------
// Kernel 1b: build worklist from final counts. 1 block, 1 wave, ~2us.
// wl[0] = nm_total (<= 155); wl[1+i] = (p<<8)|mt.
// ---------------------------------------------------------------------------
__global__ __launch_bounds__(64) void build_wl(
    const int* __restrict__ counts, int* __restrict__ wl)
{
    const int t = threadIdx.x;  // 0..63, single wave
    const int nm = (t < NPAIR) ? ((counts[t * CPAD] + 127) >> 7) : 0;
    int inc = nm;  // inclusive prefix sum across the wave
    #pragma unroll
    for (int d = 1; d < 64; d <<= 1) {
        const int v = __shfl_up(inc, d);
        if (t >= d) inc += v;
    }
    if (t == 63) wl[0] = inc;           // total mtiles
    const int ex = inc - nm;            // exclusive prefix
    for (int m = 0; m < nm; ++m)
        wl[1 + ex + m] = (t << 8) | m;
}

// ---------------------------------------------------------------------------
// Kernel 2: pair-grouped expert GEMM, DIRECT output. (Unchanged from R4.)
//   Split K-step, 2 LDS buffers, depth-2 prefetch, 3 blocks/CU:
//     vmcnt(6) ; bar ; ds_read->regs ; lgkmcnt(0) ; bar ;
//     STAGE(t+2 -> just-read buffer) ; MFMA
//   Worklist grid + XCD decode, XOR chunk swizzle (src+read), counted vmcnt,
//   setprio around MFMA cluster.
// ---------------------------------------------------------------------------
__global__ __launch_bounds__(256, 3) void moe_gemm(
    const __hip_bfloat16* __restrict__ xb,   // [NTOK][D] bf16
    const __hip_bfloat16* __restrict__ wkt,  // [E][D(out)][D(in)] bf16 (B^T)
    const float* __restrict__ bk,            // [E][D]
    const int* __restrict__ counts,          // [NPAIR*CPAD] line-padded
    const uint4* __restrict__ entries,       // [NPAIR][CAP]
    const int* __restrict__ wl,              // [1+WL_MAX]
    float* __restrict__ out)                 // [NTOK][D] fp32 (fully written)
{
    constexpr int BM = 128, BN = 128, BK = 32;
    constexpr int NT = D_ / BK;  // 16 K-steps
    // row-major [row][BK] tiles; slot s of row r holds global chunk s^f(r),
    // f(r) = (r>>1)&3  (involution via XOR)
    __shared__ __hip_bfloat16 As[2][BM * BK];       // 2 x 8 KB
    __shared__ __hip_bfloat16 Bs[2][2][BN * BK];    // 2 x 16 KB
    __shared__ uint4 ent[BM];                       // 2 KB   (total 50 KB)

    // id = g*32 + nt*8 + j ; mtile = g*8 + j ; XCD = id%8 = j for all 4 nt
    const int id = blockIdx.x;
    const int g = id >> 5, r = id & 31;
    const int nt = r >> 3;
    const int mi = g * 8 + (r & 7);
    const int nmtot = wl[0];
    if (mi >= nmtot) return;
    const int we = wl[1 + mi];
    const int p = we >> 8, mt = we & 255;
    const int cnt = counts[p * CPAD];

    // decode pair p -> (e1 < e2)
    int e1 = 0, rem = p;
    while (rem >= 7 - e1) { rem -= 7 - e1; ++e1; }
    const int e2 = e1 + 1 + rem;

    const int tid = threadIdx.x;
    const int wave = tid >> 6, lane = tid & 63;

    if (tid < BM) {
        const int idx = mt * BM + tid;
        ent[tid] = (idx < cnt) ? entries[(size_t)p * CAP + idx]
                               : make_uint4(0u, 0u, 0u, 0u);
    }
    __syncthreads();

    const int quad = lane >> 4, lr = lane & 15;
    const int wm = wave >> 1, wn = wave & 1;

    // --- staging geometry (64B contiguous per row, 16 rows per wave-call) ---
    // lane -> (row16 = lane>>2, chunk c = (lane&3) ^ f(row)); f telescopes to
    // (lane>>3)&3 because row = wave*32 + (lane>>2) and wave*32>>1 is mult of 16.
    const int r16 = lane >> 2;
    const int csel = (lane & 3) ^ ((lane >> 3) & 3);   // swizzled 16B chunk
    const int rA0 = wave * 32 + r16;                   // rows [w*32, w*32+16)
    const size_t tA0 = ent[rA0].x;
    const size_t tA1 = ent[rA0 + 16].x;
    const __hip_bfloat16* gA0 = xb + tA0 * D_ + csel * 8;
    const __hip_bfloat16* gA1 = xb + tA1 * D_ + csel * 8;
    const __hip_bfloat16* gB1 = wkt + ((size_t)e1 * D_ + nt * BN + rA0) * D_ + csel * 8;
    const __hip_bfloat16* gB2 = wkt + ((size_t)e2 * D_ + nt * BN + rA0) * D_ + csel * 8;

    // read-side swizzled slot (per-lane constant): quad ^ ((lr>>1)&3)
    const int so = (quad ^ ((lr >> 1) & 3)) * 8;

    f32x4 accA[4][4], accB[4][4];
    #pragma unroll
    for (int i = 0; i < 4; ++i)
        #pragma unroll
        for (int j = 0; j < 4; ++j) {
            accA[i][j] = (f32x4){0.f, 0.f, 0.f, 0.f};
            accB[i][j] = (f32x4){0.f, 0.f, 0.f, 0.f};
        }

    // 6 async loads per wave per STAGE -> vmcnt counts in units of 6
#define STAGE(buf, k0) do {                                        \
        __hip_bfloat16* aB  = &As[buf][wave * 1024];               \
        __hip_bfloat16* b1B = &Bs[buf][0][wave * 1024];            \
        __hip_bfloat16* b2B = &Bs[buf][1][wave * 1024];            \
        async_load16(gA0 + (k0), aB);                              \
        async_load16(gA1 + (k0), aB + 512);                        \
        async_load16(gB1 + (k0), b1B);                             \
        async_load16(gB1 + 16 * D_ + (k0), b1B + 512);             \
        async_load16(gB2 + (k0), b2B);                             \
        async_load16(gB2 + 16 * D_ + (k0), b2B + 512);             \
    } while (0)

#define READS(buf) do {                                                        \
        _Pragma("unroll")                                                      \
        for (int i = 0; i < 4; ++i)                                            \
            a[i] = *(const short8*)(&As[buf][(wm * 64 + i * 16 + lr) * 32 + so]); \
        _Pragma("unroll")                                                      \
        for (int j = 0; j < 4; ++j) {                                          \
            b1v[j] = *(const short8*)(&Bs[buf][0][(wn * 64 + j * 16 + lr) * 32 + so]); \
            b2v[j] = *(const short8*)(&Bs[buf][1][(wn * 64 + j * 16 + lr) * 32 + so]); \
        }                                                                      \
    } while (0)

#define MFMAS() do {                                                           \
        __builtin_amdgcn_s_setprio(1);                                         \
        _Pragma("unroll")                                                      \
        for (int i = 0; i < 4; ++i)                                            \
            _Pragma("unroll")                                                  \
            for (int j = 0; j < 4; ++j) {                                      \
                accA[i][j] = __builtin_amdgcn_mfma_f32_16x16x32_bf16(          \
                    a[i], b1v[j], accA[i][j], 0, 0, 0);                        \
                accB[i][j] = __builtin_amdgcn_mfma_f32_16x16x32_bf16(          \
                    a[i], b2v[j], accB[i][j], 0, 0, 0);                        \
            }                                                                  \
        __builtin_amdgcn_s_setprio(0);                                         \
    } while (0)

    // prologue: tiles 0 and 1 in flight (12 outstanding VMEM ops per wave)
    STAGE(0, 0);
    STAGE(1, BK);

    // steady state (split K-step): tile t lands -> read to regs -> drain
    // lgkm -> barrier -> refill the SAME buffer with tile t+2 -> MFMA.
    for (int t = 0; t < NT - 1; ++t) {
        short8 a[4], b1v[4], b2v[4];
        asm volatile("s_waitcnt vmcnt(6)" ::: "memory");
        __builtin_amdgcn_s_barrier();
        READS(t & 1);
        asm volatile("s_waitcnt lgkmcnt(0)" ::: "memory");
        __builtin_amdgcn_s_barrier();
        if (t + 2 < NT) STAGE(t & 1, (t + 2) * BK);
        MFMAS();
    }
    {
        short8 a[4], b1v[4], b2v[4];
        asm volatile("s_waitcnt vmcnt(0)" ::: "memory");
        __builtin_amdgcn_s_barrier();
        READS((NT - 1) & 1);
        MFMAS();
    }

#undef STAGE
#undef READS
#undef MFMAS

    const int colbase = nt * BN + wn * 64 + lr;
    float bkA[4], bkB[4];
    #pragma unroll
    for (int j = 0; j < 4; ++j) {
        bkA[j] = bk[e1 * D_ + colbase + j * 16];
        bkB[j] = bk[e2 * D_ + colbase + j * 16];
    }

    #pragma unroll
    for (int i = 0; i < 4; ++i) {
        #pragma unroll
        for (int rr = 0; rr < 4; ++rr) {
            const int row = wm * 64 + i * 16 + quad * 4 + rr;  // C: row = quad*4+reg
            if (mt * BM + row < cnt) {
                const uint4 en = ent[row];
                const float ga = __uint_as_float(en.y);
                const float gb = __uint_as_float(en.z);
                float* orow = out + (size_t)en.x * D_ + colbase;
                #pragma unroll
                for (int j = 0; j < 4; ++j)
                    orow[j * 16] = ga * (accA[i][j][rr] + bkA[j])
                                 + gb * (accB[i][j][rr] + bkB[j]);
            }
        }
    }
}

// ---------------------------------------------------------------------------
// Launch: 4 dispatches: memset, fused prep, build_wl, gemm.
// ---------------------------------------------------------------------------
extern "C" void kernel_launch(void* const* d_in, const int* in_sizes, int n_in,
                              void* d_out, int out_size, void* d_ws, size_t ws_size,
                              hipStream_t stream) {
    const float* x   = (const float*)d_in[0];
    const float* eps = (const float*)d_in[1];
    const float* Wr  = (const float*)d_in[2];
    const float* br  = (const float*)d_in[3];
    const float* Wn  = (const float*)d_in[4];
    const float* bn  = (const float*)d_in[5];
    const float* Wk  = (const float*)d_in[6];
    const float* bk  = (const float*)d_in[7];
    float* out = (float*)d_out;

    // workspace layout (256B-aligned): ~28 MB total
    char* ws = (char*)d_ws;
    size_t off = 0;
    int* counts = (int*)(ws + off);                     off += 8192;  // NPAIR*CPAD ints (3.5KB), padded
    uint4* entries = (uint4*)(ws + off);                off += (size_t)NPAIR * CAP * 16;  // 7.3 MiB
    __hip_bfloat16* xb = (__hip_bfloat16*)(ws + off);   off += (size_t)NTOK * D_ * 2;     // 16 MiB
    __hip_bfloat16* wkt = (__hip_bfloat16*)(ws + off);  off += (size_t)E_ * D_ * D_ * 2;  // 4 MiB
    int* wl = (int*)(ws + off);                         off += 1024;                      // worklist
    (void)ws_size;

    hipMemsetAsync(counts, 0, 8192, stream);   // zeroes counts[]

    prep_kernel<<<dim3(PREP_BLOCKS), dim3(256), 0, stream>>>(
        x, eps, Wr, br, Wn, bn, Wk, xb, wkt, counts, entries);
    build_wl<<<dim3(1), dim3(64), 0, stream>>>(counts, wl);
    moe_gemm<<<dim3(WL_MAX * 4), dim3(256), 0, stream>>>(
        xb, wkt, bk, counts, entries, wl, out);
}

// Round 6
// 155.570 us; speedup vs baseline: 3.0561x; 1.3423x over previous
//
#include <hip/hip_runtime.h>
#include <hip/hip_bf16.h>
#include <math.h>

// Problem constants
#define B_    8
#define T_    2048
#define NTOK  (B_ * T_)   // 16384 tokens
#define D_    512
#define E_    8
#define NPAIR 28          // unordered expert pairs (top-2 always distinct)
#define CAP   NTOK        // per-pair bucket capacity (worst case)
#define CPAD  32          // counts padding: one counter per 128B line

// worklist: wl[0] = total mtiles; wl[1+i] = (pair<<8)|mtile.
// Sum ceil(cnt_p/128) <= 128 + 27 = 155 -> pad to 160 (multiple of 8 for XCD map)
#define WL_MAX 160

// router: 1024 blocks x 256 thr; 16 tok/block, 4 tok/wave.
#define RV_TOK    16
#define RV_THR    256
#define XS_STRIDE 132
#define WS_FLOATS 2108

// fused prep kernel: router blocks + transpose blocks
#define PREP_ROUTER_BLOCKS (NTOK / RV_TOK)        // 1024
#define PREP_TRANS_BLOCKS  (16 * 16 * E_)          // 2048
#define PREP_BLOCKS (PREP_ROUTER_BLOCKS + PREP_TRANS_BLOCKS)  // 3072

typedef __attribute__((ext_vector_type(4))) float f32x4;
typedef __attribute__((ext_vector_type(8))) short short8;  // 8 bf16 (MFMA a/b frag)

__device__ __forceinline__ void async_load16(const void* g, void* l) {
    __builtin_amdgcn_global_load_lds(
        (const __attribute__((address_space(1))) unsigned int*)g,
        (__attribute__((address_space(3))) unsigned int*)l,
        16, 0, 0);
}

// ---------------------------------------------------------------------------
// Kernel 1 (fused prep): transpose_wk  U  router(+bucket). Unchanged from R5.
// Pure grid of independent blocks; two-level bucket (LDS hist -> line-padded
// counter atomics); no cross-block sync.
// ---------------------------------------------------------------------------
__global__ __launch_bounds__(256) void prep_kernel(
    const float* __restrict__ x,     // [NTOK][D]
    const float* __restrict__ eps,   // [NTOK][E]
    const float* __restrict__ Wr,    // [D][E]
    const float* __restrict__ br,    // [E]
    const float* __restrict__ Wn,    // [D][E]
    const float* __restrict__ bn,    // [E]
    const float* __restrict__ Wk,    // [E][D][D]
    __hip_bfloat16* __restrict__ xb,   // out: [NTOK][D] bf16
    __hip_bfloat16* __restrict__ wkt,  // out: [E][D][D] bf16 (B^T)
    int* __restrict__ counts,          // [NPAIR*CPAD] pre-zeroed (line-padded)
    uint4* __restrict__ entries)       // [NPAIR][CAP]
{
    __shared__ float smem[RV_TOK * XS_STRIDE + WS_FLOATS];  // 16.9 KB
    __shared__ int hist[NPAIR];
    __shared__ int basep[NPAIR];
    const int bid = blockIdx.x, tid = threadIdx.x;

    if (bid < PREP_ROUTER_BLOCKS) {
        // ------------------------- router body -------------------------
        float* xs  = smem;                         // [RV_TOK][XS_STRIDE]
        float* wsh = smem + RV_TOK * XS_STRIDE;    // skewed [128][16]

        const int tok0 = bid * RV_TOK;
        const int lane = tid & 63, wv = tid >> 6;
        const int kidx = lane >> 2, ts = lane & 3;
        const int tl = wv * 4 + ts;                // this lane's token
        const int wk = tid >> 1, wh = tid & 1;     // W stager: row, half

        if (tid < NPAIR) hist[tid] = 0;

        float acc[16];  // [0..7]=x.Wr per expert, [8..15]=x.Wn
        #pragma unroll
        for (int c = 0; c < 16; ++c) acc[c] = 0.f;

        for (int kc = 0; kc < D_; kc += 128) {
            // stage x chunk [16 tok][128 k] + fused bf16 convert/store
            #pragma unroll
            for (int it = 0; it < 2; ++it) {
                const int f   = it * RV_THR + tid;      // f32x4 index in [0,512)
                const int row = f >> 5, col = (f & 31) * 4;
                const f32x4 v = *(const f32x4*)(x + (size_t)(tok0 + row) * D_ + kc + col);
                *(f32x4*)(xs + row * XS_STRIDE + col) = v;
                union { __hip_bfloat16 h[4]; uint2 u; } cv;
                cv.h[0] = __float2bfloat16(v.x); cv.h[1] = __float2bfloat16(v.y);
                cv.h[2] = __float2bfloat16(v.z); cv.h[3] = __float2bfloat16(v.w);
                *(uint2*)(xb + (size_t)(tok0 + row) * D_ + kc + col) = cv.u;
            }
            // stage W chunk [128 k][16 c] skewed; cols 0-7 = Wr, 8-15 = Wn
            {
                const float* src = (wh ? Wn : Wr) + (size_t)(kc + wk) * E_;
                const f32x4 w0 = *(const f32x4*)(src);
                const f32x4 w1 = *(const f32x4*)(src + 4);
                float* dst = wsh + wk * 16 + (wk >> 3) * 4 + wh * 8;
                *(f32x4*)(dst)     = w0;
                *(f32x4*)(dst + 4) = w1;
            }
            __syncthreads();

            // compute: this lane's 8 k-values of the chunk (k = kidx*8 + kk)
            const float* xra = xs + tl * XS_STRIDE + kidx * 8;
            const f32x4 xa0 = *(const f32x4*)(xra);
            const f32x4 xa1 = *(const f32x4*)(xra + 4);
            const float* wbase = wsh + kidx * 132;  // (kidx*8)*16 + kidx*4
            #pragma unroll
            for (int kk = 0; kk < 8; ++kk) {
                const float xav = (kk < 4) ? xa0[kk] : xa1[kk - 4];
                const float* wrow = wbase + kk * 16;
                #pragma unroll
                for (int c4 = 0; c4 < 4; ++c4) {
                    const f32x4 w = *(const f32x4*)(wrow + c4 * 4);
                    #pragma unroll
                    for (int c = 0; c < 4; ++c)
                        acc[c4 * 4 + c] = fmaf(xav, w[c], acc[c4 * 4 + c]);
                }
            }
            __syncthreads();
        }

        // reduce across the 16 kidx lanes (stride 4): xor 4,8,16,32
        #pragma unroll
        for (int off = 4; off < 64; off <<= 1) {
            #pragma unroll
            for (int c = 0; c < 16; ++c)
                acc[c] += __shfl_xor(acc[c], off);
        }

        // ---- top-2 + two-level bucket (LDS hist -> padded global atomics) ----
        int p_ = 0, l_ = 0, tok_ = 0;
        float gae_ = 0.f, gbe_ = 0.f;
        const bool writer = (lane < 4);
        if (writer) {  // kidx==0 lanes hold full dots for token tl
            tok_ = tok0 + tl;
            float nv[8];
            #pragma unroll
            for (int e = 0; e < 8; ++e) {
                const float nl = acc[8 + e] + bn[e];
                // jax.nn.softplus = max(z,0) + log1p(exp(-|z|))
                const float sp = fmaxf(nl, 0.f) + log1pf(expf(-fabsf(nl)));
                nv[e] = acc[e] + br[e] + eps[(size_t)tok_ * E_ + e] * sp;
            }
            // top-2, lax.top_k tie semantics (lowest index wins ties)
            int i1 = 0; float v1 = nv[0];
            #pragma unroll
            for (int e = 1; e < 8; ++e)
                if (nv[e] > v1) { v1 = nv[e]; i1 = e; }
            int i2 = -1; float v2 = -3.4e38f;
            #pragma unroll
            for (int e = 0; e < 8; ++e)
                if (e != i1 && nv[e] > v2) { v2 = nv[e]; i2 = e; }
            const float t  = expf(v2 - v1);
            const float g1 = 1.f / (1.f + t);
            const float g2 = t / (1.f + t);
            const int aa = min(i1, i2), bb = max(i1, i2);
            gae_ = (i1 < i2) ? g1 : g2;   // gate of expert aa
            gbe_ = (i1 < i2) ? g2 : g1;   // gate of expert bb
            p_ = aa * (15 - aa) / 2 + (bb - aa - 1);
            l_ = atomicAdd(&hist[p_], 1);            // LDS atomic (cheap)
        }
        __syncthreads();
        if (tid < NPAIR && hist[tid] > 0)
            basep[tid] = atomicAdd(counts + tid * CPAD, hist[tid]);  // own line
        __syncthreads();
        if (writer)
            entries[(size_t)p_ * CAP + basep[p_] + l_] =
                make_uint4((unsigned)tok_, __float_as_uint(gae_),
                           __float_as_uint(gbe_), 0u);
    } else {
        // ------------------------ transpose body -----------------------
        const int idx = bid - PREP_ROUTER_BLOCKS;   // [0, 2048)
        const int e  = idx >> 8;
        const int rem = idx & 255;
        const int d0 = (rem & 15) * 32;
        const int h0 = (rem >> 4) * 32;
        const int tx = tid & 31, ty = tid >> 5;     // 32 x 8
        float (*tile)[33] = reinterpret_cast<float(*)[33]>(smem);

        const float* src = Wk + ((size_t)e * D_ + d0) * D_ + h0;
        #pragma unroll
        for (int r = ty; r < 32; r += 8)
            tile[r][tx] = src[(size_t)r * D_ + tx];
        __syncthreads();
        __hip_bfloat16* dst = wkt + ((size_t)e * D_ + h0) * D_ + d0;
        #pragma unroll
        for (int r = ty; r < 32; r += 8)
            dst[(size_t)r * D_ + tx] = __float2bfloat16(tile[tx][r]);
    }
    // (no fence, no done-counter: kernel boundary publishes everything)
}

// ---------------------------------------------------------------------------
// Kernel 1b: build worklist from final counts. 1 block, 1 wave, ~2us.
// wl[0] = nm_total (<= 155); wl[1+i] = (p<<8)|mt.
// ---------------------------------------------------------------------------
__global__ __launch_bounds__(64) void build_wl(
    const int* __restrict__ counts, int* __restrict__ wl)
{
    const int t = threadIdx.x;  // 0..63, single wave
    const int nm = (t < NPAIR) ? ((counts[t * CPAD] + 127) >> 7) : 0;
    int inc = nm;  // inclusive prefix sum across the wave
    #pragma unroll
    for (int d = 1; d < 64; d <<= 1) {
        const int v = __shfl_up(inc, d);
        if (t >= d) inc += v;
    }
    if (t == 63) wl[0] = inc;           // total mtiles
    const int ex = inc - nm;            // exclusive prefix
    for (int m = 0; m < nm; ++m)
        wl[1 + ex + m] = (t << 8) | m;
}

// ---------------------------------------------------------------------------
// Kernel 2: pair-grouped expert GEMM, DIRECT output.
//   R6 fix vs R5 (93us): __launch_bounds__(256,3) -> (256,2). The 3-waves/EU
//   bound capped the unified reg budget at ~170/wave < the ~212 this kernel
//   needs (128 acc AGPRs + frags + addr). Compiler spilled the accumulators
//   to scratch: VGPR_Count 84, WRITE_SIZE 167MB vs 32MB of actual output
//   (5x write amplification = scratch evictions). At (256,2) the budget is
//   256/wave -> no spill; residency 2 blocks/CU (same as the 47.8us R0).
//   Everything else unchanged: split K-step, counted vmcnt(6), 2 LDS
//   buffers, worklist grid + XCD decode, XOR chunk swizzle, setprio.
// ---------------------------------------------------------------------------
__global__ __launch_bounds__(256, 2) void moe_gemm(
    const __hip_bfloat16* __restrict__ xb,   // [NTOK][D] bf16
    const __hip_bfloat16* __restrict__ wkt,  // [E][D(out)][D(in)] bf16 (B^T)
    const float* __restrict__ bk,            // [E][D]
    const int* __restrict__ counts,          // [NPAIR*CPAD] line-padded
    const uint4* __restrict__ entries,       // [NPAIR][CAP]
    const int* __restrict__ wl,              // [1+WL_MAX]
    float* __restrict__ out)                 // [NTOK][D] fp32 (fully written)
{
    constexpr int BM = 128, BN = 128, BK = 32;
    constexpr int NT = D_ / BK;  // 16 K-steps
    // row-major [row][BK] tiles; slot s of row r holds global chunk s^f(r),
    // f(r) = (r>>1)&3  (involution via XOR)
    __shared__ __hip_bfloat16 As[2][BM * BK];       // 2 x 8 KB
    __shared__ __hip_bfloat16 Bs[2][2][BN * BK];    // 2 x 16 KB
    __shared__ uint4 ent[BM];                       // 2 KB   (total 50 KB)

    // id = g*32 + nt*8 + j ; mtile = g*8 + j ; XCD = id%8 = j for all 4 nt
    const int id = blockIdx.x;
    const int g = id >> 5, r = id & 31;
    const int nt = r >> 3;
    const int mi = g * 8 + (r & 7);
    const int nmtot = wl[0];
    if (mi >= nmtot) return;
    const int we = wl[1 + mi];
    const int p = we >> 8, mt = we & 255;
    const int cnt = counts[p * CPAD];

    // decode pair p -> (e1 < e2)
    int e1 = 0, rem = p;
    while (rem >= 7 - e1) { rem -= 7 - e1; ++e1; }
    const int e2 = e1 + 1 + rem;

    const int tid = threadIdx.x;
    const int wave = tid >> 6, lane = tid & 63;

    if (tid < BM) {
        const int idx = mt * BM + tid;
        ent[tid] = (idx < cnt) ? entries[(size_t)p * CAP + idx]
                               : make_uint4(0u, 0u, 0u, 0u);
    }
    __syncthreads();

    const int quad = lane >> 4, lr = lane & 15;
    const int wm = wave >> 1, wn = wave & 1;

    // --- staging geometry (64B contiguous per row, 16 rows per wave-call) ---
    // lane -> (row16 = lane>>2, chunk c = (lane&3) ^ f(row)); f telescopes to
    // (lane>>3)&3 because row = wave*32 + (lane>>2) and wave*32>>1 is mult of 16.
    const int r16 = lane >> 2;
    const int csel = (lane & 3) ^ ((lane >> 3) & 3);   // swizzled 16B chunk
    const int rA0 = wave * 32 + r16;                   // rows [w*32, w*32+16)
    const size_t tA0 = ent[rA0].x;
    const size_t tA1 = ent[rA0 + 16].x;
    const __hip_bfloat16* gA0 = xb + tA0 * D_ + csel * 8;
    const __hip_bfloat16* gA1 = xb + tA1 * D_ + csel * 8;
    const __hip_bfloat16* gB1 = wkt + ((size_t)e1 * D_ + nt * BN + rA0) * D_ + csel * 8;
    const __hip_bfloat16* gB2 = wkt + ((size_t)e2 * D_ + nt * BN + rA0) * D_ + csel * 8;

    // read-side swizzled slot (per-lane constant): quad ^ ((lr>>1)&3)
    const int so = (quad ^ ((lr >> 1) & 3)) * 8;

    f32x4 accA[4][4], accB[4][4];
    #pragma unroll
    for (int i = 0; i < 4; ++i)
        #pragma unroll
        for (int j = 0; j < 4; ++j) {
            accA[i][j] = (f32x4){0.f, 0.f, 0.f, 0.f};
            accB[i][j] = (f32x4){0.f, 0.f, 0.f, 0.f};
        }

    // 6 async loads per wave per STAGE -> vmcnt counts in units of 6
#define STAGE(buf, k0) do {                                        \
        __hip_bfloat16* aB  = &As[buf][wave * 1024];               \
        __hip_bfloat16* b1B = &Bs[buf][0][wave * 1024];            \
        __hip_bfloat16* b2B = &Bs[buf][1][wave * 1024];            \
        async_load16(gA0 + (k0), aB);                              \
        async_load16(gA1 + (k0), aB + 512);                        \
        async_load16(gB1 + (k0), b1B);                             \
        async_load16(gB1 + 16 * D_ + (k0), b1B + 512);             \
        async_load16(gB2 + (k0), b2B);                             \
        async_load16(gB2 + 16 * D_ + (k0), b2B + 512);             \
    } while (0)

#define READS(buf) do {                                                        \
        _Pragma("unroll")                                                      \
        for (int i = 0; i < 4; ++i)                                            \
            a[i] = *(const short8*)(&As[buf][(wm * 64 + i * 16 + lr) * 32 + so]); \
        _Pragma("unroll")                                                      \
        for (int j = 0; j < 4; ++j) {                                          \
            b1v[j] = *(const short8*)(&Bs[buf][0][(wn * 64 + j * 16 + lr) * 32 + so]); \
            b2v[j] = *(const short8*)(&Bs[buf][1][(wn * 64 + j * 16 + lr) * 32 + so]); \
        }                                                                      \
    } while (0)

#define MFMAS() do {                                                           \
        __builtin_amdgcn_s_setprio(1);                                         \
        _Pragma("unroll")                                                      \
        for (int i = 0; i < 4; ++i)                                            \
            _Pragma("unroll")                                                  \
            for (int j = 0; j < 4; ++j) {                                      \
                accA[i][j] = __builtin_amdgcn_mfma_f32_16x16x32_bf16(          \
                    a[i], b1v[j], accA[i][j], 0, 0, 0);                        \
                accB[i][j] = __builtin_amdgcn_mfma_f32_16x16x32_bf16(          \
                    a[i], b2v[j], accB[i][j], 0, 0, 0);                        \
            }                                                                  \
        __builtin_amdgcn_s_setprio(0);                                         \
    } while (0)

    // prologue: tiles 0 and 1 in flight (12 outstanding VMEM ops per wave)
    STAGE(0, 0);
    STAGE(1, BK);

    // steady state (split K-step): tile t lands -> read to regs -> drain
    // lgkm -> barrier -> refill the SAME buffer with tile t+2 -> MFMA.
    for (int t = 0; t < NT - 1; ++t) {
        short8 a[4], b1v[4], b2v[4];
        asm volatile("s_waitcnt vmcnt(6)" ::: "memory");
        __builtin_amdgcn_s_barrier();
        READS(t & 1);
        asm volatile("s_waitcnt lgkmcnt(0)" ::: "memory");
        __builtin_amdgcn_s_barrier();
        if (t + 2 < NT) STAGE(t & 1, (t + 2) * BK);
        MFMAS();
    }
    {
        short8 a[4], b1v[4], b2v[4];
        asm volatile("s_waitcnt vmcnt(0)" ::: "memory");
        __builtin_amdgcn_s_barrier();
        READS((NT - 1) & 1);
        MFMAS();
    }

#undef STAGE
#undef READS
#undef MFMAS

    const int colbase = nt * BN + wn * 64 + lr;
    float bkA[4], bkB[4];
    #pragma unroll
    for (int j = 0; j < 4; ++j) {
        bkA[j] = bk[e1 * D_ + colbase + j * 16];
        bkB[j] = bk[e2 * D_ + colbase + j * 16];
    }

    #pragma unroll
    for (int i = 0; i < 4; ++i) {
        #pragma unroll
        for (int rr = 0; rr < 4; ++rr) {
            const int row = wm * 64 + i * 16 + quad * 4 + rr;  // C: row = quad*4+reg
            if (mt * BM + row < cnt) {
                const uint4 en = ent[row];
                const float ga = __uint_as_float(en.y);
                const float gb = __uint_as_float(en.z);
                float* orow = out + (size_t)en.x * D_ + colbase;
                #pragma unroll
                for (int j = 0; j < 4; ++j)
                    orow[j * 16] = ga * (accA[i][j][rr] + bkA[j])
                                 + gb * (accB[i][j][rr] + bkB[j]);
            }
        }
    }
}

// ---------------------------------------------------------------------------
// Launch: 4 dispatches: memset, fused prep, build_wl, gemm.
// ---------------------------------------------------------------------------
extern "C" void kernel_launch(void* const* d_in, const int* in_sizes, int n_in,
                              void* d_out, int out_size, void* d_ws, size_t ws_size,
                              hipStream_t stream) {
    const float* x   = (const float*)d_in[0];
    const float* eps = (const float*)d_in[1];
    const float* Wr  = (const float*)d_in[2];
    const float* br  = (const float*)d_in[3];
    const float* Wn  = (const float*)d_in[4];
    const float* bn  = (const float*)d_in[5];
    const float* Wk  = (const float*)d_in[6];
    const float* bk  = (const float*)d_in[7];
    float* out = (float*)d_out;

    // workspace layout (256B-aligned): ~28 MB total
    char* ws = (char*)d_ws;
    size_t off = 0;
    int* counts = (int*)(ws + off);                     off += 8192;  // NPAIR*CPAD ints (3.5KB), padded
    uint4* entries = (uint4*)(ws + off);                off += (size_t)NPAIR * CAP * 16;  // 7.3 MiB
    __hip_bfloat16* xb = (__hip_bfloat16*)(ws + off);   off += (size_t)NTOK * D_ * 2;     // 16 MiB
    __hip_bfloat16* wkt = (__hip_bfloat16*)(ws + off);  off += (size_t)E_ * D_ * D_ * 2;  // 4 MiB
    int* wl = (int*)(ws + off);                         off += 1024;                      // worklist
    (void)ws_size;

    hipMemsetAsync(counts, 0, 8192, stream);   // zeroes counts[]

    prep_kernel<<<dim3(PREP_BLOCKS), dim3(256), 0, stream>>>(
        x, eps, Wr, br, Wn, bn, Wk, xb, wkt, counts, entries);
    build_wl<<<dim3(1), dim3(64), 0, stream>>>(counts, wl);
    moe_gemm<<<dim3(WL_MAX * 4), dim3(256), 0, stream>>>(
        xb, wkt, bk, counts, entries, wl, out);
}

// Round 7
// 152.337 us; speedup vs baseline: 3.1210x; 1.0212x over previous
//
#include <hip/hip_runtime.h>
#include <hip/hip_bf16.h>
#include <math.h>

// Problem constants
#define B_    8
#define T_    2048
#define NTOK  (B_ * T_)   // 16384 tokens
#define D_    512
#define E_    8
#define NPAIR 28          // unordered expert pairs (top-2 always distinct)
#define CAP   NTOK        // per-pair bucket capacity (worst case)
#define CPAD  32          // counts padding: one counter per 128B line

// gemm mtile grain = 64 rows. Sum ceil(cnt_p/64) <= 256 + 27 = 283 -> 288
#define GEMM_MTILES 288   // multiple of 8 for the XCD id decode

// router: 1024 blocks x 256 thr; 16 tok/block, 4 tok/wave.
#define RV_TOK    16
#define RV_THR    256
#define XS_STRIDE 132
#define WS_FLOATS 2108

// fused prep kernel: router blocks + transpose blocks
#define PREP_ROUTER_BLOCKS (NTOK / RV_TOK)        // 1024
#define PREP_TRANS_BLOCKS  (16 * 16 * E_)          // 2048
#define PREP_BLOCKS (PREP_ROUTER_BLOCKS + PREP_TRANS_BLOCKS)  // 3072

typedef __attribute__((ext_vector_type(4))) float f32x4;
typedef __attribute__((ext_vector_type(8))) short short8;  // 8 bf16 (MFMA a/b frag)

__device__ __forceinline__ void async_load16(const void* g, void* l) {
    __builtin_amdgcn_global_load_lds(
        (const __attribute__((address_space(1))) unsigned int*)g,
        (__attribute__((address_space(3))) unsigned int*)l,
        16, 0, 0);
}

// ---------------------------------------------------------------------------
// Kernel 1 (fused prep): transpose_wk  U  router(+bucket). Unchanged from R6.
// Pure grid of independent blocks; two-level bucket (LDS hist -> line-padded
// counter atomics); no cross-block sync.
// ---------------------------------------------------------------------------
__global__ __launch_bounds__(256) void prep_kernel(
    const float* __restrict__ x,     // [NTOK][D]
    const float* __restrict__ eps,   // [NTOK][E]
    const float* __restrict__ Wr,    // [D][E]
    const float* __restrict__ br,    // [E]
    const float* __restrict__ Wn,    // [D][E]
    const float* __restrict__ bn,    // [E]
    const float* __restrict__ Wk,    // [E][D][D]
    __hip_bfloat16* __restrict__ xb,   // out: [NTOK][D] bf16
    __hip_bfloat16* __restrict__ wkt,  // out: [E][D][D] bf16 (B^T)
    int* __restrict__ counts,          // [NPAIR*CPAD] pre-zeroed (line-padded)
    uint4* __restrict__ entries)       // [NPAIR][CAP]
{
    __shared__ float smem[RV_TOK * XS_STRIDE + WS_FLOATS];  // 16.9 KB
    __shared__ int hist[NPAIR];
    __shared__ int basep[NPAIR];
    const int bid = blockIdx.x, tid = threadIdx.x;

    if (bid < PREP_ROUTER_BLOCKS) {
        // ------------------------- router body -------------------------
        float* xs  = smem;                         // [RV_TOK][XS_STRIDE]
        float* wsh = smem + RV_TOK * XS_STRIDE;    // skewed [128][16]

        const int tok0 = bid * RV_TOK;
        const int lane = tid & 63, wv = tid >> 6;
        const int kidx = lane >> 2, ts = lane & 3;
        const int tl = wv * 4 + ts;                // this lane's token
        const int wk = tid >> 1, wh = tid & 1;     // W stager: row, half

        if (tid < NPAIR) hist[tid] = 0;

        float acc[16];  // [0..7]=x.Wr per expert, [8..15]=x.Wn
        #pragma unroll
        for (int c = 0; c < 16; ++c) acc[c] = 0.f;

        for (int kc = 0; kc < D_; kc += 128) {
            // stage x chunk [16 tok][128 k] + fused bf16 convert/store
            #pragma unroll
            for (int it = 0; it < 2; ++it) {
                const int f   = it * RV_THR + tid;      // f32x4 index in [0,512)
                const int row = f >> 5, col = (f & 31) * 4;
                const f32x4 v = *(const f32x4*)(x + (size_t)(tok0 + row) * D_ + kc + col);
                *(f32x4*)(xs + row * XS_STRIDE + col) = v;
                union { __hip_bfloat16 h[4]; uint2 u; } cv;
                cv.h[0] = __float2bfloat16(v.x); cv.h[1] = __float2bfloat16(v.y);
                cv.h[2] = __float2bfloat16(v.z); cv.h[3] = __float2bfloat16(v.w);
                *(uint2*)(xb + (size_t)(tok0 + row) * D_ + kc + col) = cv.u;
            }
            // stage W chunk [128 k][16 c] skewed; cols 0-7 = Wr, 8-15 = Wn
            {
                const float* src = (wh ? Wn : Wr) + (size_t)(kc + wk) * E_;
                const f32x4 w0 = *(const f32x4*)(src);
                const f32x4 w1 = *(const f32x4*)(src + 4);
                float* dst = wsh + wk * 16 + (wk >> 3) * 4 + wh * 8;
                *(f32x4*)(dst)     = w0;
                *(f32x4*)(dst + 4) = w1;
            }
            __syncthreads();

            // compute: this lane's 8 k-values of the chunk (k = kidx*8 + kk)
            const float* xra = xs + tl * XS_STRIDE + kidx * 8;
            const f32x4 xa0 = *(const f32x4*)(xra);
            const f32x4 xa1 = *(const f32x4*)(xra + 4);
            const float* wbase = wsh + kidx * 132;  // (kidx*8)*16 + kidx*4
            #pragma unroll
            for (int kk = 0; kk < 8; ++kk) {
                const float xav = (kk < 4) ? xa0[kk] : xa1[kk - 4];
                const float* wrow = wbase + kk * 16;
                #pragma unroll
                for (int c4 = 0; c4 < 4; ++c4) {
                    const f32x4 w = *(const f32x4*)(wrow + c4 * 4);
                    #pragma unroll
                    for (int c = 0; c < 4; ++c)
                        acc[c4 * 4 + c] = fmaf(xav, w[c], acc[c4 * 4 + c]);
                }
            }
            __syncthreads();
        }

        // reduce across the 16 kidx lanes (stride 4): xor 4,8,16,32
        #pragma unroll
        for (int off = 4; off < 64; off <<= 1) {
            #pragma unroll
            for (int c = 0; c < 16; ++c)
                acc[c] += __shfl_xor(acc[c], off);
        }

        // ---- top-2 + two-level bucket (LDS hist -> padded global atomics) ----
        int p_ = 0, l_ = 0, tok_ = 0;
        float gae_ = 0.f, gbe_ = 0.f;
        const bool writer = (lane < 4);
        if (writer) {  // kidx==0 lanes hold full dots for token tl
            tok_ = tok0 + tl;
            float nv[8];
            #pragma unroll
            for (int e = 0; e < 8; ++e) {
                const float nl = acc[8 + e] + bn[e];
                // jax.nn.softplus = max(z,0) + log1p(exp(-|z|))
                const float sp = fmaxf(nl, 0.f) + log1pf(expf(-fabsf(nl)));
                nv[e] = acc[e] + br[e] + eps[(size_t)tok_ * E_ + e] * sp;
            }
            // top-2, lax.top_k tie semantics (lowest index wins ties)
            int i1 = 0; float v1 = nv[0];
            #pragma unroll
            for (int e = 1; e < 8; ++e)
                if (nv[e] > v1) { v1 = nv[e]; i1 = e; }
            int i2 = -1; float v2 = -3.4e38f;
            #pragma unroll
            for (int e = 0; e < 8; ++e)
                if (e != i1 && nv[e] > v2) { v2 = nv[e]; i2 = e; }
            const float t  = expf(v2 - v1);
            const float g1 = 1.f / (1.f + t);
            const float g2 = t / (1.f + t);
            const int aa = min(i1, i2), bb = max(i1, i2);
            gae_ = (i1 < i2) ? g1 : g2;   // gate of expert aa
            gbe_ = (i1 < i2) ? g2 : g1;   // gate of expert bb
            p_ = aa * (15 - aa) / 2 + (bb - aa - 1);
            l_ = atomicAdd(&hist[p_], 1);            // LDS atomic (cheap)
        }
        __syncthreads();
        if (tid < NPAIR && hist[tid] > 0)
            basep[tid] = atomicAdd(counts + tid * CPAD, hist[tid]);  // own line
        __syncthreads();
        if (writer)
            entries[(size_t)p_ * CAP + basep[p_] + l_] =
                make_uint4((unsigned)tok_, __float_as_uint(gae_),
                           __float_as_uint(gbe_), 0u);
    } else {
        // ------------------------ transpose body -----------------------
        const int idx = bid - PREP_ROUTER_BLOCKS;   // [0, 2048)
        const int e  = idx >> 8;
        const int rem = idx & 255;
        const int d0 = (rem & 15) * 32;
        const int h0 = (rem >> 4) * 32;
        const int tx = tid & 31, ty = tid >> 5;     // 32 x 8
        float (*tile)[33] = reinterpret_cast<float(*)[33]>(smem);

        const float* src = Wk + ((size_t)e * D_ + d0) * D_ + h0;
        #pragma unroll
        for (int r = ty; r < 32; r += 8)
            tile[r][tx] = src[(size_t)r * D_ + tx];
        __syncthreads();
        __hip_bfloat16* dst = wkt + ((size_t)e * D_ + h0) * D_ + d0;
        #pragma unroll
        for (int r = ty; r < 32; r += 8)
            dst[(size_t)r * D_ + tx] = __float2bfloat16(tile[tx][r]);
    }
    // (no fence, no done-counter: kernel boundary publishes everything)
}

// ---------------------------------------------------------------------------
// Kernel 2: pair-grouped expert GEMM, DIRECT output.
//   R7 vs R6:
//   * build_wl dispatch ELIMINATED: each block derives (pair, mtile) from
//     counts[] with a 28-lane shfl prefix scan (~100cyc, L2 hits). One
//     fewer launch boundary (~10us measured-by-subtraction in R6).
//   * BM 128 -> 64: acc halves to 64 VGPR -> total ~145 regs fits
//     __launch_bounds__(256,3) WITHOUT spill (R5's spill needed 212 > 170
//     cap; watch VGPR_Count>=130 & WRITE_SIZE~33MB to confirm). LDS 41 KB
//     -> 3 blocks/CU, 3 waves/SIMD; ~1132 blocks -> better balance, finer
//     tail. Per-wave tile 32x64 (wm=wave>>1, wn=wave&1), 16 MFMA/K-step.
//   * staging: 5 gload_lds/wave/stage (1 A + 4 B) -> counted vmcnt(5).
//     XOR chunk swizzle unchanged (row bases all mult of 16 -> csel
//     telescopes identically on src and read sides).
// ---------------------------------------------------------------------------
__global__ __launch_bounds__(256, 3) void moe_gemm(
    const __hip_bfloat16* __restrict__ xb,   // [NTOK][D] bf16
    const __hip_bfloat16* __restrict__ wkt,  // [E][D(out)][D(in)] bf16 (B^T)
    const float* __restrict__ bk,            // [E][D]
    const int* __restrict__ counts,          // [NPAIR*CPAD] line-padded
    const uint4* __restrict__ entries,       // [NPAIR][CAP]
    float* __restrict__ out)                 // [NTOK][D] fp32 (fully written)
{
    constexpr int BM = 64, BN = 128, BK = 32;
    constexpr int NT = D_ / BK;  // 16 K-steps
    // row-major [row][BK] tiles; slot s of row r holds global chunk s^f(r),
    // f(r) = (r>>1)&3  (involution via XOR)
    __shared__ __hip_bfloat16 As[2][BM * BK];       // 2 x 4 KB
    __shared__ __hip_bfloat16 Bs[2][2][BN * BK];    // 2 x 16 KB
    __shared__ uint4 ent[BM];                       // 1 KB   (total 41 KB)

    // id = g*32 + nt*8 + j ; mtile mi = g*8 + j ; XCD = id%8 = j for all 4 nt
    const int id = blockIdx.x;
    const int g = id >> 5, rdec = id & 31;
    const int nt = rdec >> 3;
    const int mi = g * 8 + (rdec & 7);

    const int tid = threadIdx.x;
    const int wave = tid >> 6, lane = tid & 63;

    // ---- inline worklist: lane-parallel scan of ceil(counts/64) ----
    const int cval = (lane < NPAIR) ? counts[lane * CPAD] : 0;
    const int nm = (cval + 63) >> 6;
    int inc = nm;
    #pragma unroll
    for (int d = 1; d < 32; d <<= 1) {
        const int v = __shfl_up(inc, d);
        if (lane >= d) inc += v;
    }
    const int total = __shfl(inc, NPAIR - 1);
    if (mi >= total) return;
    const int ex = inc - nm;   // exclusive prefix for this lane's pair
    const unsigned long long hit =
        __ballot(lane < NPAIR && mi >= ex && mi < ex + nm);
    const int p = __ffsll(hit) - 1;
    const int mt = mi - __shfl(ex, p);
    const int cnt = __shfl(cval, p);

    // decode pair p -> (e1 < e2)
    int e1 = 0, rem = p;
    while (rem >= 7 - e1) { rem -= 7 - e1; ++e1; }
    const int e2 = e1 + 1 + rem;

    if (tid < BM) {
        const int idx = mt * BM + tid;
        ent[tid] = (idx < cnt) ? entries[(size_t)p * CAP + idx]
                               : make_uint4(0u, 0u, 0u, 0u);
    }
    __syncthreads();

    const int quad = lane >> 4, lr = lane & 15;
    const int wm = wave >> 1, wn = wave & 1;   // wave tile: rows wm*32, cols wn*64

    // --- staging geometry (64B contiguous per row, 16 rows per call) ---
    // A: wave w stages rows [w*16, w*16+16); B1/B2: rows [w*32, w*32+32).
    // chunk csel = (lane&3) ^ ((lane>>3)&3)  (row bases are mult of 16 ->
    // f(row) telescopes to (r16>>1)&3 = (lane>>3)&3).
    const int r16 = lane >> 2;
    const int csel = (lane & 3) ^ ((lane >> 3) & 3);   // swizzled 16B chunk
    const size_t tA0 = ent[wave * 16 + r16].x;
    const __hip_bfloat16* gA0 = xb + tA0 * D_ + csel * 8;
    const __hip_bfloat16* gB1 = wkt + ((size_t)e1 * D_ + nt * BN + wave * 32 + r16) * D_ + csel * 8;
    const __hip_bfloat16* gB2 = wkt + ((size_t)e2 * D_ + nt * BN + wave * 32 + r16) * D_ + csel * 8;

    // read-side swizzled slot (per-lane constant): quad ^ ((lr>>1)&3)
    const int so = (quad ^ ((lr >> 1) & 3)) * 8;

    f32x4 accA[2][4], accB[2][4];
    #pragma unroll
    for (int i = 0; i < 2; ++i)
        #pragma unroll
        for (int j = 0; j < 4; ++j) {
            accA[i][j] = (f32x4){0.f, 0.f, 0.f, 0.f};
            accB[i][j] = (f32x4){0.f, 0.f, 0.f, 0.f};
        }

    // 5 async loads per wave per STAGE -> vmcnt counts in units of 5
#define STAGE(buf, k0) do {                                        \
        __hip_bfloat16* aB  = &As[buf][wave * 512];                \
        __hip_bfloat16* b1B = &Bs[buf][0][wave * 1024];            \
        __hip_bfloat16* b2B = &Bs[buf][1][wave * 1024];            \
        async_load16(gA0 + (k0), aB);                              \
        async_load16(gB1 + (k0), b1B);                             \
        async_load16(gB1 + 16 * D_ + (k0), b1B + 512);             \
        async_load16(gB2 + (k0), b2B);                             \
        async_load16(gB2 + 16 * D_ + (k0), b2B + 512);             \
    } while (0)

#define READS(buf) do {                                                        \
        _Pragma("unroll")                                                      \
        for (int i = 0; i < 2; ++i)                                            \
            a[i] = *(const short8*)(&As[buf][(wm * 32 + i * 16 + lr) * 32 + so]); \
        _Pragma("unroll")                                                      \
        for (int j = 0; j < 4; ++j) {                                          \
            b1v[j] = *(const short8*)(&Bs[buf][0][(wn * 64 + j * 16 + lr) * 32 + so]); \
            b2v[j] = *(const short8*)(&Bs[buf][1][(wn * 64 + j * 16 + lr) * 32 + so]); \
        }                                                                      \
    } while (0)

#define MFMAS() do {                                                           \
        __builtin_amdgcn_s_setprio(1);                                         \
        _Pragma("unroll")                                                      \
        for (int i = 0; i < 2; ++i)                                            \
            _Pragma("unroll")                                                  \
            for (int j = 0; j < 4; ++j) {                                      \
                accA[i][j] = __builtin_amdgcn_mfma_f32_16x16x32_bf16(          \
                    a[i], b1v[j], accA[i][j], 0, 0, 0);                        \
                accB[i][j] = __builtin_amdgcn_mfma_f32_16x16x32_bf16(          \
                    a[i], b2v[j], accB[i][j], 0, 0, 0);                        \
            }                                                                  \
        __builtin_amdgcn_s_setprio(0);                                         \
    } while (0)

    // prologue: tiles 0 and 1 in flight (10 outstanding VMEM ops per wave)
    STAGE(0, 0);
    STAGE(1, BK);

    // steady state (split K-step): tile t lands -> read to regs -> drain
    // lgkm -> barrier -> refill the SAME buffer with tile t+2 -> MFMA.
    for (int t = 0; t < NT - 1; ++t) {
        short8 a[2], b1v[4], b2v[4];
        asm volatile("s_waitcnt vmcnt(5)" ::: "memory");
        __builtin_amdgcn_s_barrier();
        READS(t & 1);
        asm volatile("s_waitcnt lgkmcnt(0)" ::: "memory");
        __builtin_amdgcn_s_barrier();
        if (t + 2 < NT) STAGE(t & 1, (t + 2) * BK);
        MFMAS();
    }
    {
        short8 a[2], b1v[4], b2v[4];
        asm volatile("s_waitcnt vmcnt(0)" ::: "memory");
        __builtin_amdgcn_s_barrier();
        READS((NT - 1) & 1);
        MFMAS();
    }

#undef STAGE
#undef READS
#undef MFMAS

    const int colbase = nt * BN + wn * 64 + lr;
    float bkA[4], bkB[4];
    #pragma unroll
    for (int j = 0; j < 4; ++j) {
        bkA[j] = bk[e1 * D_ + colbase + j * 16];
        bkB[j] = bk[e2 * D_ + colbase + j * 16];
    }

    #pragma unroll
    for (int i = 0; i < 2; ++i) {
        #pragma unroll
        for (int rr = 0; rr < 4; ++rr) {
            const int row = wm * 32 + i * 16 + quad * 4 + rr;  // C: row = quad*4+reg
            if (mt * BM + row < cnt) {
                const uint4 en = ent[row];
                const float ga = __uint_as_float(en.y);
                const float gb = __uint_as_float(en.z);
                float* orow = out + (size_t)en.x * D_ + colbase;
                #pragma unroll
                for (int j = 0; j < 4; ++j)
                    orow[j * 16] = ga * (accA[i][j][rr] + bkA[j])
                                 + gb * (accB[i][j][rr] + bkB[j]);
            }
        }
    }
}

// ---------------------------------------------------------------------------
// Launch: 3 dispatches: memset, fused prep, gemm (worklist inlined).
// ---------------------------------------------------------------------------
extern "C" void kernel_launch(void* const* d_in, const int* in_sizes, int n_in,
                              void* d_out, int out_size, void* d_ws, size_t ws_size,
                              hipStream_t stream) {
    const float* x   = (const float*)d_in[0];
    const float* eps = (const float*)d_in[1];
    const float* Wr  = (const float*)d_in[2];
    const float* br  = (const float*)d_in[3];
    const float* Wn  = (const float*)d_in[4];
    const float* bn  = (const float*)d_in[5];
    const float* Wk  = (const float*)d_in[6];
    const float* bk  = (const float*)d_in[7];
    float* out = (float*)d_out;

    // workspace layout (256B-aligned): ~28 MB total
    char* ws = (char*)d_ws;
    size_t off = 0;
    int* counts = (int*)(ws + off);                     off += 8192;  // NPAIR*CPAD ints (3.5KB), padded
    uint4* entries = (uint4*)(ws + off);                off += (size_t)NPAIR * CAP * 16;  // 7.3 MiB
    __hip_bfloat16* xb = (__hip_bfloat16*)(ws + off);   off += (size_t)NTOK * D_ * 2;     // 16 MiB
    __hip_bfloat16* wkt = (__hip_bfloat16*)(ws + off);  off += (size_t)E_ * D_ * D_ * 2;  // 4 MiB
    (void)ws_size;

    hipMemsetAsync(counts, 0, 8192, stream);   // zeroes counts[]

    prep_kernel<<<dim3(PREP_BLOCKS), dim3(256), 0, stream>>>(
        x, eps, Wr, br, Wn, bn, Wk, xb, wkt, counts, entries);
    moe_gemm<<<dim3(GEMM_MTILES * 4), dim3(256), 0, stream>>>(
        xb, wkt, bk, counts, entries, out);
}